// Round 17
// baseline (83.759 us; speedup 1.0000x reference)
//
#include <hip/hip_runtime.h>

#define LOG_2PI_F 1.8378770664093453f

constexpr int BC = 1024, CC = 16, PV = 16, LV = 64, BB = 4;
constexpr int CH = (PV + 1) * BC;
constexpr int SLAB = BB * CC * LV;           // 4096
constexpr int SLABTOT = 2 * SLAB + BB * CC;  // 8256
constexpr int NB2 = 512;                     // 2-cap grid
constexpr int NSLAB_SM = 32;
constexpr size_t WBF_ELEMS = (size_t)CC * BC * LV * PV;   // 16.7M shorts
constexpr size_t POSE_ELEMS = (size_t)BC * 64 * 16;       // shorts
constexpr size_t ACT_ELEMS = (size_t)BC * 64;             // floats

typedef __attribute__((ext_vector_type(4))) short short4v;
typedef __attribute__((ext_vector_type(8))) short short8v;
typedef __attribute__((ext_vector_type(16))) float f32x16;

union ABfrag { short8v v; short4v h[2]; unsigned short u[8]; };

__device__ __forceinline__ unsigned short f2bf(float f) {
  unsigned u = __float_as_uint(f);
  u += 0x7fffu + ((u >> 16) & 1u);  // RNE
  return (unsigned short)(u >> 16);
}

__device__ __forceinline__ short8v cvt8(const float4 a, const float4 b) {
  ABfrag f;
  f.u[0] = f2bf(a.x); f.u[1] = f2bf(a.y); f.u[2] = f2bf(a.z); f.u[3] = f2bf(a.w);
  f.u[4] = f2bf(b.x); f.u[5] = f2bf(b.y); f.u[6] = f2bf(b.z); f.u[7] = f2bf(b.w);
  return f.v;
}

// ===== 2-caps-per-block sweep (round-15 shape: 512 thr / 8 waves / 2c per
// wave), grid 512 = one scheduling round. Cross-cap S1/S2 accumulate in LDS
// Sacc (NOT registers - rounds 8/9/13 spilled on register state held across
// compute).
// PASS1 NEW: BOTH caps' bf16 W fragments prefetched up front (wfN[4], 16
// VGPR, no cvt) -> cap1's W-load latency hides under cap0 compute. This is
// safe where rounds 4/9 were not: no raw fp32 held, no convert-later.
// PASS0 keeps convert-immediately per cap (fp32 source).
// MFMA v_mfma_f32_32x32x16_bf16: A m=lane&31,k=8h+j ;
// C/D col=lane&31,row=(reg&3)+8*(reg>>2)+4*h [m74/m101].
// Phase A: SWAPPED mfma(W,pose) -> l-sum in-register + 1 shfl_xor(32).
// Phase B: mfma(pose,W), r-sum in-register, h==0 lanes write/add Sacc.
// PASS1 computes mu_s/T_s in-block from Sred (33KB broadcast, L2-resident).
template <int PASS>
__global__ __launch_bounds__(512, 4) void em_sweep2(
    const float* __restrict__ x, const float* __restrict__ W,
    const float* __restrict__ SredIn, const float* __restrict__ beta_v,
    const float* __restrict__ beta_a, const float* __restrict__ lam,
    float* __restrict__ Spart,
    unsigned short* __restrict__ WbfC, unsigned short* __restrict__ poseC,
    float* __restrict__ actC) {
  const int bid = blockIdx.x, t = threadIdx.x;
  const int w = t >> 6, lane = t & 63;
  const int ln31 = lane & 31, h = lane >> 5;
  const int cbase = 2 * w;

  float* slab = Spart + (size_t)bid * SLABTOT;

  __shared__ __align__(16) unsigned short pbf[2][64][20];  // pitch 40B
  __shared__ float act_s[2][64];
  __shared__ float T_s[64];
  __shared__ float sr_s[64];
  __shared__ float sc_s[64][17];
  __shared__ float rh2[16][64];
  __shared__ __align__(16) float mu_s[64][64];
  __shared__ float lsum_s[64][8];
  __shared__ float Sacc[SLABTOT];  // cross-cap accumulator (LDS, not regs!)

  // ---- PASS1: prefetch BOTH caps' bf16 W fragments (issue before compute) ----
  short8v wfP[4], wfN[4];
  if (PASS == 1) {
#pragma unroll
    for (int k = 0; k < 4; ++k) {
      const int cl_ = k >> 1, lh = k & 1;
      const size_t off0 = ((size_t)(cbase + cl_) * BC + bid) * 1024 +
                          (lh * 32 + ln31) * 16 + 8 * h;
      wfP[k] = *reinterpret_cast<const short8v*>(WbfC + off0);
    }
#pragma unroll
    for (int k = 0; k < 4; ++k) {
      const int cl_ = k >> 1, lh = k & 1;
      const size_t off1 = ((size_t)(cbase + cl_) * BC + bid + NB2) * 1024 +
                          (lh * 32 + ln31) * 16 + 8 * h;
      wfN[k] = *reinterpret_cast<const short8v*>(WbfC + off1);
    }
#pragma unroll
    for (int k = 0; k < 4; ++k) asm volatile("" : "+v"(wfP[k]));
#pragma unroll
    for (int k = 0; k < 4; ++k) asm volatile("" : "+v"(wfN[k]));
  }

  // ---- prologue: stage pose/act for BOTH caps ----
  if (PASS == 1) {
    if (t < 256) {  // pose from bf16 cache, clean 16B chunks
      const int cap = t >> 7, tt = t & 127;
      const int r = tt >> 1, half = tt & 1;
      const int i = bid + cap * NB2;
      const int4 v = *reinterpret_cast<const int4*>(
          poseC + ((size_t)i * 64 + r) * 16 + 8 * half);
      union { int4 q; short4v s[2]; } u;
      u.q = v;
      *reinterpret_cast<short4v*>(&pbf[cap][r][8 * half]) = u.s[0];
      *reinterpret_cast<short4v*>(&pbf[cap][r][8 * half + 4]) = u.s[1];
    }
    if (t < 128) {
      const int cap = t >> 6, r = t & 63;
      act_s[cap][r] = actC[(size_t)(bid + cap * NB2) * 64 + r];
    }
    if (t < 64) sr_s[t] = 0.f;
    // ---- in-block mu/T from Sred ----
    {
      const int bc = t >> 3, part = t & 7;
      const float inv = 1.f / SredIn[2 * SLAB + bc];
      float lsl = 0.f;
#pragma unroll
      for (int q = 0; q < 8; ++q) {
        const int idx = bc * 64 + part * 8 + q;
        const float m = SredIn[idx] * inv;
        const float s2 = fmaxf(SredIn[SLAB + idx] * inv - m * m, 0.01f);
        lsl += logf(s2);
        mu_s[bc][part * 8 + q] = m;
      }
      lsum_s[bc][part] = lsl;
    }
    __syncthreads();
    if (t < 64) {
      float lsum = 0.f;
#pragma unroll
      for (int q = 0; q < 8; ++q) lsum += lsum_s[t][q];
      const float sr = SredIn[2 * SLAB + t];
      const float z = lam[0] * (beta_a[t & 15] - (64.f * beta_v[0] + lsum) * sr);
      const float ac = 1.f / (1.f + expf(-z));
      T_s[t] = logf(ac) - 0.5f * (64.f * LOG_2PI_F + lsum);
    }
    __syncthreads();
  } else {
    {
      const int cap = t >> 8, tt = t & 255;
      const int b = tt >> 6, p = (tt >> 2) & 15, q = tt & 3;
      const int i = bid + cap * NB2;
      const float4 v = *reinterpret_cast<const float4*>(
          x + ((size_t)(b * CH + p * BC + i)) * 16 + 4 * q);
      pbf[cap][b * 16 + 4 * q + 0][p] = f2bf(v.x);
      pbf[cap][b * 16 + 4 * q + 1][p] = f2bf(v.y);
      pbf[cap][b * 16 + 4 * q + 2][p] = f2bf(v.z);
      pbf[cap][b * 16 + 4 * q + 3][p] = f2bf(v.w);
    }
    if (t < 128) {
      const int cap = t >> 6, r = t & 63;
      const int b = r >> 4, xy = r & 15;
      const float a = x[((size_t)(b * CH + PV * BC + bid + cap * NB2)) * 16 + xy];
      act_s[cap][r] = a;
      actC[(size_t)(bid + cap * NB2) * 64 + r] = a;
    }
    __syncthreads();
    // persist pose-bf16 (reads LDS after barrier)
    if (t < 256) {
      const int cap = t >> 7, tt = t & 127;
      const int r = tt >> 1, half = tt & 1;
      const int i = bid + cap * NB2;
      union { int4 q; short4v s[2]; } u;
      u.s[0] = *reinterpret_cast<const short4v*>(&pbf[cap][r][8 * half]);
      u.s[1] = *reinterpret_cast<const short4v*>(&pbf[cap][r][8 * half + 4]);
      *reinterpret_cast<int4*>(poseC + ((size_t)i * 64 + r) * 16 + 8 * half) = u.q;
    }
  }

  const f32x16 zero16 = {};

#pragma unroll
  for (int cap = 0; cap < 2; ++cap) {
    const int i = bid + cap * NB2;
    // ---- W fragments for this cap ----
    short8v wf[4];
    if (PASS == 1) {
      // prefetched; cap is compile-time constant here -> static select
#pragma unroll
      for (int k = 0; k < 4; ++k) wf[k] = (cap == 0) ? wfP[k] : wfN[k];
    } else {
#pragma unroll
      for (int k = 0; k < 4; ++k) {
        const int cl_ = k >> 1, lh = k & 1;
        const float* src = W + ((size_t)(cbase + cl_) * BC + i) * 1024 +
                           (lh * 32 + ln31) * 16 + 8 * h;
        const float4 v0 = *reinterpret_cast<const float4*>(src);
        const float4 v1 = *reinterpret_cast<const float4*>(src + 4);
        wf[k] = cvt8(v0, v1);  // convert immediately (spill-proof)
      }
#pragma unroll
      for (int k = 0; k < 4; ++k) asm volatile("" : "+v"(wf[k]));  // pin live
#pragma unroll
      for (int k = 0; k < 4; ++k) {
        const int cl_ = k >> 1, lh = k & 1;
        const size_t off = ((size_t)(cbase + cl_) * BC + i) * 1024 +
                           (lh * 32 + ln31) * 16 + 8 * h;
        *reinterpret_cast<short8v*>(WbfC + off) = wf[k];
      }
    }

    if (PASS == 1) {
      // ---- phase A (swapped): in-register l-sum ----
#pragma unroll
      for (int rowhalf = 0; rowhalf < 2; ++rowhalf) {
        ABfrag A;
        {
          const int r = rowhalf * 32 + ln31;
          A.h[0] = *reinterpret_cast<const short4v*>(&pbf[cap][r][8 * h]);
          A.h[1] = *reinterpret_cast<const short4v*>(&pbf[cap][r][8 * h + 4]);
        }
        const int b = (rowhalf * 32 + ln31) >> 4;
#pragma unroll
        for (int cl_ = 0; cl_ < 2; ++cl_) {
          float sc = 0.f;
#pragma unroll
          for (int lh = 0; lh < 2; ++lh) {
            const f32x16 acc = __builtin_amdgcn_mfma_f32_32x32x16_bf16(
                wf[cl_ * 2 + lh], A.v, zero16, 0, 0, 0);
            const float* mrow = &mu_s[b * CC + cbase + cl_][lh * 32 + 4 * h];
#pragma unroll
            for (int g = 0; g < 4; ++g) {
              const float4 m4 = *reinterpret_cast<const float4*>(mrow + 8 * g);
              float d;
              d = acc[4 * g + 0] - m4.x; sc = fmaf(d, d, sc);
              d = acc[4 * g + 1] - m4.y; sc = fmaf(d, d, sc);
              d = acc[4 * g + 2] - m4.z; sc = fmaf(d, d, sc);
              d = acc[4 * g + 3] - m4.w; sc = fmaf(d, d, sc);
            }
          }
          sc += __shfl_xor(sc, 32, 64);
          if (h == 0) sc_s[rowhalf * 32 + ln31][cbase + cl_] = sc;
        }
      }
      __syncthreads();
      // ---- softmax over c ----
      {
        const int r = t & 63, cq = t >> 6, b = r >> 4;
        float s[16];
#pragma unroll
        for (int cc = 0; cc < 16; ++cc) s[cc] = T_s[b * CC + cc] - sc_s[r][cc];
        float m = s[0];
#pragma unroll
        for (int cc = 1; cc < 16; ++cc) m = fmaxf(m, s[cc]);
        float den = 0.f;
#pragma unroll
        for (int cc = 0; cc < 16; ++cc) { s[cc] = __expf(s[cc] - m); den += s[cc]; }
        const float a = act_s[cap][r] / den;
#pragma unroll
        for (int k = 0; k < 2; ++k) {
          const int cc = 2 * cq + k;
          const float rh = fmaxf(s[cc] * a, 0.01f);
          rh2[cc][r] = rh;
          atomicAdd(&sr_s[b * CC + cc], rh);
        }
      }
      __syncthreads();
    }

    // ---- phase B: S1/S2 -> LDS accumulator ----
#pragma unroll
    for (int pair = 0; pair < 2; ++pair) {
      ABfrag A;
      {
        const int r = pair * 32 + ln31;
        A.h[0] = *reinterpret_cast<const short4v*>(&pbf[cap][r][8 * h]);
        A.h[1] = *reinterpret_cast<const short4v*>(&pbf[cap][r][8 * h + 4]);
      }
      float p1[4][2] = {}, p2[4][2] = {};
#pragma unroll
      for (int cl_ = 0; cl_ < 2; ++cl_) {
        float rq[16];
        if (PASS == 1) {
#pragma unroll
          for (int g = 0; g < 4; ++g) {
            const float4 v = *reinterpret_cast<const float4*>(
                &rh2[cbase + cl_][pair * 32 + 8 * g + 4 * h]);
            rq[4 * g + 0] = v.x; rq[4 * g + 1] = v.y;
            rq[4 * g + 2] = v.z; rq[4 * g + 3] = v.w;
          }
        } else {
#pragma unroll
          for (int g = 0; g < 4; ++g) {
            const float4 v = *reinterpret_cast<const float4*>(
                &act_s[cap][pair * 32 + 8 * g + 4 * h]);
            rq[4 * g + 0] = fmaxf(v.x * 0.0625f, 0.01f);
            rq[4 * g + 1] = fmaxf(v.y * 0.0625f, 0.01f);
            rq[4 * g + 2] = fmaxf(v.z * 0.0625f, 0.01f);
            rq[4 * g + 3] = fmaxf(v.w * 0.0625f, 0.01f);
          }
        }
#pragma unroll
        for (int lh = 0; lh < 2; ++lh) {
          const f32x16 acc = __builtin_amdgcn_mfma_f32_32x32x16_bf16(
              A.v, wf[cl_ * 2 + lh], zero16, 0, 0, 0);
          const int t4 = cl_ * 2 + lh;
#pragma unroll
          for (int j = 0; j < 16; ++j) {
            const float v = acc[j];
            const float rv = rq[j] * v;
            p1[t4][j >> 3] += rv;
            p2[t4][j >> 3] = fmaf(rv, v, p2[t4][j >> 3]);
          }
        }
      }
#pragma unroll
      for (int t4 = 0; t4 < 4; ++t4)
#pragma unroll
        for (int bh = 0; bh < 2; ++bh) {
          float v1 = p1[t4][bh]; v1 += __shfl_xor(v1, 32, 64);
          float v2 = p2[t4][bh]; v2 += __shfl_xor(v2, 32, 64);
          const int b = pair * 2 + bh, c = cbase + (t4 >> 1);
          const int idx = (b * CC + c) * LV + (t4 & 1) * 32 + ln31;
          if (h == 0) {
            if (cap == 0) { Sacc[idx] = v1; Sacc[SLAB + idx] = v2; }
            else          { Sacc[idx] += v1; Sacc[SLAB + idx] += v2; }
          }
        }
    }
  }

  // ---- Sr + slab store ----
  if (PASS == 1) {
    if (t < 64) Sacc[2 * SLAB + t] = sr_s[t];
  } else {
    if (t < 64) {
      const int b = t >> 4;
      float s = 0.f;
#pragma unroll
      for (int cp = 0; cp < 2; ++cp)
#pragma unroll
        for (int xy = 0; xy < 16; ++xy)
          s += fmaxf(act_s[cp][b * 16 + xy] * 0.0625f, 0.01f);
      Sacc[2 * SLAB + t] = s;
    }
  }
  __syncthreads();
  for (int idx = t; idx < SLABTOT; idx += 512) slab[idx] = Sacc[idx];
}

// ---- two-stage tree reduce, plain stores ----
__global__ void reduce_stageA(const float* __restrict__ Spart,
                              float* __restrict__ Spart2) {
  const int idx = blockIdx.x * 256 + threadIdx.x;
  if (idx >= SLABTOT) return;
  const float* base = Spart + (size_t)(blockIdx.y * 32) * SLABTOT + idx;
  float a = 0.f;
#pragma unroll 8
  for (int s = 0; s < 32; ++s) a += base[(size_t)s * SLABTOT];
  Spart2[(size_t)blockIdx.y * SLABTOT + idx] = a;
}

__global__ void reduce_stageB(const float* __restrict__ Spart2,
                              float* __restrict__ Sred, int nchunk) {
  const int idx = blockIdx.x * 256 + threadIdx.x;
  if (idx >= SLABTOT) return;
  float a = 0.f;
  for (int s = 0; s < nchunk; ++s) a += Spart2[(size_t)s * SLABTOT + idx];
  Sred[idx] = a;
}

// ---- final stats (512 threads) ----
__global__ void stats_final(const float* __restrict__ Sred,
                            const float* __restrict__ beta_v,
                            const float* __restrict__ beta_a,
                            const float* __restrict__ lam,
                            float* __restrict__ out) {
  __shared__ float lsum_s[64][8];
  const int t = threadIdx.x;
  const int bc = t >> 3, part = t & 7;
  const float inv = 1.f / Sred[2 * SLAB + bc];
  float lsl = 0.f;
#pragma unroll
  for (int q = 0; q < 8; ++q) {
    const int l = part * 8 + q;
    const int idx = bc * 64 + l;
    const float m = Sred[idx] * inv;
    const float s2 = fmaxf(Sred[SLAB + idx] * inv - m * m, 0.01f);
    lsl += logf(s2);
    out[(size_t)(bc >> 4) * 1040 + (bc & 15) * 64 + l] = m;
  }
  lsum_s[bc][part] = lsl;
  __syncthreads();
  if (t < 64) {
    float lsum = 0.f;
#pragma unroll
    for (int q = 0; q < 8; ++q) lsum += lsum_s[t][q];
    const float sr = Sred[2 * SLAB + t];
    const float z = lam[0] * (beta_a[t & 15] - (64.f * beta_v[0] + lsum) * sr);
    out[(size_t)(t >> 4) * 1040 + 1024 + (t & 15)] = 1.f / (1.f + expf(-z));
  }
}

// ===== legacy single-cap fallback (round-12 proven; small-ws only) =====
template <int PASS>
__global__ __launch_bounds__(512, 4) void em_sweep_legacy(
    const float* __restrict__ x, const float* __restrict__ W,
    const float* __restrict__ mu, const float* __restrict__ T,
    float* __restrict__ Spart, int nslab) {
  const int i = blockIdx.x, t = threadIdx.x;
  const int w = t >> 6, lane = t & 63;
  const int ln31 = lane & 31, h = lane >> 5;
  const int cbase = 2 * w;

  float* S1p = Spart + (size_t)(i % nslab) * SLABTOT;
  float* S2p = S1p + SLAB;
  float* Srp = S1p + 2 * SLAB;

  __shared__ __align__(16) unsigned short pbf[64][20];
  __shared__ float act_s[64];
  __shared__ float T_s[64];
  __shared__ float sr_s[64];
  __shared__ float sc_s[64][17];
  __shared__ float rh2[16][64];
  __shared__ __align__(16) float mu_s[64][64];

  short8v wf[4];
#pragma unroll
  for (int k = 0; k < 4; ++k) {
    const int cl_ = k >> 1, lh = k & 1;
    const float* src = W + ((size_t)(cbase + cl_) * BC + i) * 1024 +
                       (lh * 32 + ln31) * 16 + 8 * h;
    const float4 v0 = *reinterpret_cast<const float4*>(src);
    const float4 v1 = *reinterpret_cast<const float4*>(src + 4);
    wf[k] = cvt8(v0, v1);
  }
#pragma unroll
  for (int k = 0; k < 4; ++k) asm volatile("" : "+v"(wf[k]));

  if (t < 256) {
    const int b = t >> 6, p = (t >> 2) & 15, q = t & 3;
    const float4 v = *reinterpret_cast<const float4*>(
        x + ((size_t)(b * CH + p * BC + i)) * 16 + 4 * q);
    pbf[b * 16 + 4 * q + 0][p] = f2bf(v.x);
    pbf[b * 16 + 4 * q + 1][p] = f2bf(v.y);
    pbf[b * 16 + 4 * q + 2][p] = f2bf(v.z);
    pbf[b * 16 + 4 * q + 3][p] = f2bf(v.w);
  }
  if (t < 64) {
    const int b = t >> 4, xy = t & 15;
    act_s[t] = x[((size_t)(b * CH + PV * BC + i)) * 16 + xy];
    if (PASS == 1) { T_s[t] = T[t]; sr_s[t] = 0.f; }
  }
  if (PASS == 1) {
    const float4* msrc = reinterpret_cast<const float4*>(mu);
    float4* mdst = reinterpret_cast<float4*>(&mu_s[0][0]);
    mdst[t] = msrc[t];
    mdst[t + 512] = msrc[t + 512];
  }
  __syncthreads();

  const f32x16 zero16 = {};

  if (PASS == 1) {
#pragma unroll
    for (int rowhalf = 0; rowhalf < 2; ++rowhalf) {
      ABfrag A;
      {
        const int r = rowhalf * 32 + ln31;
        A.h[0] = *reinterpret_cast<const short4v*>(&pbf[r][8 * h]);
        A.h[1] = *reinterpret_cast<const short4v*>(&pbf[r][8 * h + 4]);
      }
      const int b = (rowhalf * 32 + ln31) >> 4;
#pragma unroll
      for (int cl_ = 0; cl_ < 2; ++cl_) {
        float sc = 0.f;
#pragma unroll
        for (int lh = 0; lh < 2; ++lh) {
          const f32x16 acc = __builtin_amdgcn_mfma_f32_32x32x16_bf16(
              wf[cl_ * 2 + lh], A.v, zero16, 0, 0, 0);
          const float* mrow = &mu_s[b * CC + cbase + cl_][lh * 32 + 4 * h];
#pragma unroll
          for (int g = 0; g < 4; ++g) {
            const float4 m4 = *reinterpret_cast<const float4*>(mrow + 8 * g);
            float d;
            d = acc[4 * g + 0] - m4.x; sc = fmaf(d, d, sc);
            d = acc[4 * g + 1] - m4.y; sc = fmaf(d, d, sc);
            d = acc[4 * g + 2] - m4.z; sc = fmaf(d, d, sc);
            d = acc[4 * g + 3] - m4.w; sc = fmaf(d, d, sc);
          }
        }
        sc += __shfl_xor(sc, 32, 64);
        if (h == 0) sc_s[rowhalf * 32 + ln31][cbase + cl_] = sc;
      }
    }
    __syncthreads();
    {
      const int r = t & 63, cq = t >> 6, b = r >> 4;
      float s[16];
#pragma unroll
      for (int cc = 0; cc < 16; ++cc) s[cc] = T_s[b * CC + cc] - sc_s[r][cc];
      float m = s[0];
#pragma unroll
      for (int cc = 1; cc < 16; ++cc) m = fmaxf(m, s[cc]);
      float den = 0.f;
#pragma unroll
      for (int cc = 0; cc < 16; ++cc) { s[cc] = __expf(s[cc] - m); den += s[cc]; }
      const float a = act_s[r] / den;
#pragma unroll
      for (int k = 0; k < 2; ++k) {
        const int cc = 2 * cq + k;
        const float rh = fmaxf(s[cc] * a, 0.01f);
        rh2[cc][r] = rh;
        atomicAdd(&sr_s[b * CC + cc], rh);
      }
    }
    __syncthreads();
  }

#pragma unroll
  for (int pair = 0; pair < 2; ++pair) {
    ABfrag A;
    {
      const int r = pair * 32 + ln31;
      A.h[0] = *reinterpret_cast<const short4v*>(&pbf[r][8 * h]);
      A.h[1] = *reinterpret_cast<const short4v*>(&pbf[r][8 * h + 4]);
    }
    float p1[4][2] = {}, p2[4][2] = {};
#pragma unroll
    for (int cl_ = 0; cl_ < 2; ++cl_) {
      float rq[16];
      if (PASS == 1) {
#pragma unroll
        for (int g = 0; g < 4; ++g) {
          const float4 v = *reinterpret_cast<const float4*>(
              &rh2[cbase + cl_][pair * 32 + 8 * g + 4 * h]);
          rq[4 * g + 0] = v.x; rq[4 * g + 1] = v.y;
          rq[4 * g + 2] = v.z; rq[4 * g + 3] = v.w;
        }
      } else {
#pragma unroll
        for (int g = 0; g < 4; ++g) {
          const float4 v = *reinterpret_cast<const float4*>(
              &act_s[pair * 32 + 8 * g + 4 * h]);
          rq[4 * g + 0] = fmaxf(v.x * 0.0625f, 0.01f);
          rq[4 * g + 1] = fmaxf(v.y * 0.0625f, 0.01f);
          rq[4 * g + 2] = fmaxf(v.z * 0.0625f, 0.01f);
          rq[4 * g + 3] = fmaxf(v.w * 0.0625f, 0.01f);
        }
      }
#pragma unroll
      for (int lh = 0; lh < 2; ++lh) {
        const f32x16 acc = __builtin_amdgcn_mfma_f32_32x32x16_bf16(
            A.v, wf[cl_ * 2 + lh], zero16, 0, 0, 0);
        const int t4 = cl_ * 2 + lh;
#pragma unroll
        for (int j = 0; j < 16; ++j) {
          const float v = acc[j];
          const float rv = rq[j] * v;
          p1[t4][j >> 3] += rv;
          p2[t4][j >> 3] = fmaf(rv, v, p2[t4][j >> 3]);
        }
      }
    }
#pragma unroll
    for (int t4 = 0; t4 < 4; ++t4)
#pragma unroll
      for (int bh = 0; bh < 2; ++bh) {
        float v1 = p1[t4][bh]; v1 += __shfl_xor(v1, 32, 64);
        float v2 = p2[t4][bh]; v2 += __shfl_xor(v2, 32, 64);
        const int b = pair * 2 + bh, c = cbase + (t4 >> 1);
        const int idx = (b * CC + c) * LV + (t4 & 1) * 32 + ln31;
        if (h == 0) { atomicAdd(&S1p[idx], v1); atomicAdd(&S2p[idx], v2); }
      }
  }

  if (PASS == 1) {
    if (t < 64) atomicAdd(&Srp[t], sr_s[t]);
  } else {
    if (t < 64) {
      const int b = t >> 4;
      float s = 0.f;
#pragma unroll
      for (int xy = 0; xy < 16; ++xy) s += fmaxf(act_s[b * 16 + xy] * 0.0625f, 0.01f);
      atomicAdd(&Srp[t], s);
    }
  }
}

__global__ void reduce_slabs(const float* __restrict__ Spart, float* __restrict__ Sred,
                             int nslab, int chunk) {
  const int idx = blockIdx.x * 256 + threadIdx.x;
  if (idx >= SLABTOT) return;
  const int s0 = blockIdx.y * chunk;
  const int s1 = min(s0 + chunk, nslab);
  float a = 0.f;
#pragma unroll 8
  for (int s = s0; s < s1; s++) a += Spart[(size_t)s * SLABTOT + idx];
  atomicAdd(&Sred[idx], a);
}

template <int FINAL>
__global__ void stats_post(const float* __restrict__ Sred,
                           const float* __restrict__ beta_v,
                           const float* __restrict__ beta_a,
                           const float* __restrict__ lam,
                           float* __restrict__ mu_out, float* __restrict__ T_out,
                           float* __restrict__ out) {
  __shared__ float lsum_s[64][8];
  const int t = threadIdx.x;
  const int bc = t >> 3, part = t & 7;
  const float inv = 1.f / Sred[2 * SLAB + bc];
  float lsl = 0.f;
#pragma unroll
  for (int q = 0; q < 8; ++q) {
    const int l = part * 8 + q;
    const int idx = bc * 64 + l;
    const float m = Sred[idx] * inv;
    const float s2 = fmaxf(Sred[SLAB + idx] * inv - m * m, 0.01f);
    lsl += logf(s2);
    if (FINAL) out[(size_t)(bc >> 4) * 1040 + (bc & 15) * 64 + l] = m;
    else mu_out[idx] = m;
  }
  lsum_s[bc][part] = lsl;
  __syncthreads();
  if (t < 64) {
    float lsum = 0.f;
#pragma unroll
    for (int q = 0; q < 8; ++q) lsum += lsum_s[t][q];
    const float sr = Sred[2 * SLAB + t];
    const float z = lam[0] * (beta_a[t & 15] - (64.f * beta_v[0] + lsum) * sr);
    const float ac = 1.f / (1.f + expf(-z));
    if (FINAL) out[(size_t)(t >> 4) * 1040 + 1024 + (t & 15)] = ac;
    else T_out[t] = logf(ac) - 0.5f * (64.f * LOG_2PI_F + lsum);
  }
}

extern "C" void kernel_launch(void* const* d_in, const int* in_sizes, int n_in,
                              void* d_out, int out_size, void* d_ws, size_t ws_size,
                              hipStream_t stream) {
  const float* x = (const float*)d_in[0];
  const float* W = (const float*)d_in[1];
  const float* beta_v = (const float*)d_in[2];
  const float* beta_a = (const float*)d_in[3];
  const float* lam = (const float*)d_in[4];
  float* out = (float*)d_out;

  // cache-path layout: Spart(512 slabs) | Sred | WbfC | poseC | actC | Spart2(16)
  const size_t need_cache =
      ((size_t)NB2 * SLABTOT + SLABTOT) * sizeof(float) + WBF_ELEMS * 2 +
      POSE_ELEMS * 2 + ACT_ELEMS * sizeof(float) +
      (size_t)16 * SLABTOT * sizeof(float);

  float* Spart = (float*)d_ws;

  if (ws_size >= need_cache) {
    float* Sred = Spart + (size_t)NB2 * SLABTOT;
    unsigned short* WbfC = (unsigned short*)(Sred + SLABTOT);
    unsigned short* poseC = WbfC + WBF_ELEMS;
    float* actC = (float*)(poseC + POSE_ELEMS);
    float* Spart2 = actC + ACT_ELEMS;

    const dim3 agrid((SLABTOT + 255) / 256, 16);  // 512 slabs / 32
    const dim3 bgrid((SLABTOT + 255) / 256);
    // ---- pass 0 ----
    em_sweep2<0><<<dim3(NB2), dim3(512), 0, stream>>>(
        x, W, nullptr, beta_v, beta_a, lam, Spart, WbfC, poseC, actC);
    reduce_stageA<<<agrid, dim3(256), 0, stream>>>(Spart, Spart2);
    reduce_stageB<<<bgrid, dim3(256), 0, stream>>>(Spart2, Sred, 16);
    // ---- pass 1 (mu/T computed in-block from Sred) ----
    em_sweep2<1><<<dim3(NB2), dim3(512), 0, stream>>>(
        x, W, Sred, beta_v, beta_a, lam, Spart, WbfC, poseC, actC);
    reduce_stageA<<<agrid, dim3(256), 0, stream>>>(Spart, Spart2);
    reduce_stageB<<<bgrid, dim3(256), 0, stream>>>(Spart2, Sred, 16);
    stats_final<<<dim3(1), dim3(512), 0, stream>>>(Sred, beta_v, beta_a, lam, out);
    return;
  }

  // ---- fallback: legacy memset + atomic reduce (32 slabs, 1024 blocks) ----
  const int nslab = NSLAB_SM;
  float* Sred = Spart + (size_t)nslab * SLABTOT;
  float* muW = Sred + SLABTOT;
  float* Tw = muW + SLAB;
  const int chunk = 32;
  const dim3 rgrid((SLABTOT + 255) / 256, (nslab + chunk - 1) / chunk);

  hipMemsetAsync(Spart, 0, (size_t)nslab * SLABTOT * sizeof(float), stream);
  hipMemsetAsync(Sred, 0, SLABTOT * sizeof(float), stream);
  em_sweep_legacy<0><<<dim3(BC), dim3(512), 0, stream>>>(x, W, nullptr, nullptr, Spart, nslab);
  reduce_slabs<<<rgrid, dim3(256), 0, stream>>>(Spart, Sred, nslab, chunk);
  stats_post<0><<<dim3(1), dim3(512), 0, stream>>>(Sred, beta_v, beta_a, lam, muW, Tw, nullptr);

  hipMemsetAsync(Spart, 0, (size_t)nslab * SLABTOT * sizeof(float), stream);
  em_sweep_legacy<1><<<dim3(BC), dim3(512), 0, stream>>>(x, W, muW, Tw, Spart, nslab);
  hipMemsetAsync(Sred, 0, SLABTOT * sizeof(float), stream);
  reduce_slabs<<<rgrid, dim3(256), 0, stream>>>(Spart, Sred, nslab, chunk);
  stats_post<1><<<dim3(1), dim3(512), 0, stream>>>(Sred, beta_v, beta_a, lam, nullptr, nullptr, out);
}

// Round 18
// 80.678 us; speedup vs baseline: 1.0382x; 1.0382x over previous
//
#include <hip/hip_runtime.h>

#define LOG_2PI_F 1.8378770664093453f

constexpr int BC = 1024, CC = 16, PV = 16, LV = 64, BB = 4;
constexpr int CH = (PV + 1) * BC;
constexpr int SLAB = BB * CC * LV;           // 4096
constexpr int SLABTOT = 2 * SLAB + BB * CC;  // 8256
constexpr int NB2 = 512;                     // 2-cap grid
constexpr int NSLAB_SM = 32;
constexpr size_t WBF_ELEMS = (size_t)CC * BC * LV * PV;   // 16.7M shorts
constexpr size_t POSE_ELEMS = (size_t)BC * 64 * 16;       // shorts
constexpr size_t ACT_ELEMS = (size_t)BC * 64;             // floats

typedef __attribute__((ext_vector_type(4))) short short4v;
typedef __attribute__((ext_vector_type(8))) short short8v;
typedef __attribute__((ext_vector_type(16))) float f32x16;

union ABfrag { short8v v; short4v h[2]; unsigned short u[8]; };

__device__ __forceinline__ unsigned short f2bf(float f) {
  unsigned u = __float_as_uint(f);
  u += 0x7fffu + ((u >> 16) & 1u);  // RNE
  return (unsigned short)(u >> 16);
}

__device__ __forceinline__ short8v cvt8(const float4 a, const float4 b) {
  ABfrag f;
  f.u[0] = f2bf(a.x); f.u[1] = f2bf(a.y); f.u[2] = f2bf(a.z); f.u[3] = f2bf(a.w);
  f.u[4] = f2bf(b.x); f.u[5] = f2bf(b.y); f.u[6] = f2bf(b.z); f.u[7] = f2bf(b.w);
  return f.v;
}

// ===== 2-caps-per-block sweep (round-15 best: 512 thr / 8 waves / 2c per
// wave), grid 512. Cross-cap S1/S2 accumulate in LDS Sacc (NOT registers -
// rounds 8/9/13 spilled on register state held across compute). wf[4] dead
// before each cap's reload; convert-immediately (spill-proof).
// MFMA v_mfma_f32_32x32x16_bf16: A m=lane&31,k=8h+j ;
// C/D col=lane&31,row=(reg&3)+8*(reg>>2)+4*h [m74/m101].
// Phase A: SWAPPED mfma(W,pose) -> l-sum in-register + 1 shfl_xor(32).
// Phase B: mfma(pose,W), r-sum in-register, h==0 lanes write/add Sacc.
// PASS1 computes mu_s/T_s in-block from Sred (33KB broadcast, L2-resident).
template <int PASS>
__global__ __launch_bounds__(512, 4) void em_sweep2(
    const float* __restrict__ x, const float* __restrict__ W,
    const float* __restrict__ SredIn, const float* __restrict__ beta_v,
    const float* __restrict__ beta_a, const float* __restrict__ lam,
    float* __restrict__ Spart,
    unsigned short* __restrict__ WbfC, unsigned short* __restrict__ poseC,
    float* __restrict__ actC) {
  const int bid = blockIdx.x, t = threadIdx.x;
  const int w = t >> 6, lane = t & 63;
  const int ln31 = lane & 31, h = lane >> 5;
  const int cbase = 2 * w;

  float* slab = Spart + (size_t)bid * SLABTOT;

  __shared__ __align__(16) unsigned short pbf[2][64][20];  // pitch 40B
  __shared__ float act_s[2][64];
  __shared__ float T_s[64];
  __shared__ float sr_s[64];
  __shared__ float sc_s[64][17];
  __shared__ float rh2[16][64];
  __shared__ __align__(16) float mu_s[64][64];
  __shared__ float lsum_s[64][8];
  __shared__ float Sacc[SLABTOT];  // cross-cap accumulator (LDS, not regs!)

  // ---- prologue: stage pose/act for BOTH caps ----
  if (PASS == 1) {
    if (t < 256) {  // pose from bf16 cache, clean 16B chunks
      const int cap = t >> 7, tt = t & 127;
      const int r = tt >> 1, half = tt & 1;
      const int i = bid + cap * NB2;
      const int4 v = *reinterpret_cast<const int4*>(
          poseC + ((size_t)i * 64 + r) * 16 + 8 * half);
      union { int4 q; short4v s[2]; } u;
      u.q = v;
      *reinterpret_cast<short4v*>(&pbf[cap][r][8 * half]) = u.s[0];
      *reinterpret_cast<short4v*>(&pbf[cap][r][8 * half + 4]) = u.s[1];
    }
    if (t < 128) {
      const int cap = t >> 6, r = t & 63;
      act_s[cap][r] = actC[(size_t)(bid + cap * NB2) * 64 + r];
    }
    if (t < 64) sr_s[t] = 0.f;
    // ---- in-block mu/T from Sred ----
    {
      const int bc = t >> 3, part = t & 7;
      const float inv = 1.f / SredIn[2 * SLAB + bc];
      float lsl = 0.f;
#pragma unroll
      for (int q = 0; q < 8; ++q) {
        const int idx = bc * 64 + part * 8 + q;
        const float m = SredIn[idx] * inv;
        const float s2 = fmaxf(SredIn[SLAB + idx] * inv - m * m, 0.01f);
        lsl += logf(s2);
        mu_s[bc][part * 8 + q] = m;
      }
      lsum_s[bc][part] = lsl;
    }
    __syncthreads();
    if (t < 64) {
      float lsum = 0.f;
#pragma unroll
      for (int q = 0; q < 8; ++q) lsum += lsum_s[t][q];
      const float sr = SredIn[2 * SLAB + t];
      const float z = lam[0] * (beta_a[t & 15] - (64.f * beta_v[0] + lsum) * sr);
      const float ac = 1.f / (1.f + expf(-z));
      T_s[t] = logf(ac) - 0.5f * (64.f * LOG_2PI_F + lsum);
    }
    __syncthreads();
  } else {
    {
      const int cap = t >> 8, tt = t & 255;
      const int b = tt >> 6, p = (tt >> 2) & 15, q = tt & 3;
      const int i = bid + cap * NB2;
      const float4 v = *reinterpret_cast<const float4*>(
          x + ((size_t)(b * CH + p * BC + i)) * 16 + 4 * q);
      pbf[cap][b * 16 + 4 * q + 0][p] = f2bf(v.x);
      pbf[cap][b * 16 + 4 * q + 1][p] = f2bf(v.y);
      pbf[cap][b * 16 + 4 * q + 2][p] = f2bf(v.z);
      pbf[cap][b * 16 + 4 * q + 3][p] = f2bf(v.w);
    }
    if (t < 128) {
      const int cap = t >> 6, r = t & 63;
      const int b = r >> 4, xy = r & 15;
      const float a = x[((size_t)(b * CH + PV * BC + bid + cap * NB2)) * 16 + xy];
      act_s[cap][r] = a;
      actC[(size_t)(bid + cap * NB2) * 64 + r] = a;
    }
    __syncthreads();
    // persist pose-bf16 (reads LDS after barrier)
    if (t < 256) {
      const int cap = t >> 7, tt = t & 127;
      const int r = tt >> 1, half = tt & 1;
      const int i = bid + cap * NB2;
      union { int4 q; short4v s[2]; } u;
      u.s[0] = *reinterpret_cast<const short4v*>(&pbf[cap][r][8 * half]);
      u.s[1] = *reinterpret_cast<const short4v*>(&pbf[cap][r][8 * half + 4]);
      *reinterpret_cast<int4*>(poseC + ((size_t)i * 64 + r) * 16 + 8 * half) = u.q;
    }
  }

  const f32x16 zero16 = {};

#pragma unroll
  for (int cap = 0; cap < 2; ++cap) {
    const int i = bid + cap * NB2;
    // ---- W fragments for this cap (wf dead before reload; convert-now) ----
    short8v wf[4];
    if (PASS == 1) {
#pragma unroll
      for (int k = 0; k < 4; ++k) {
        const int cl_ = k >> 1, lh = k & 1;
        const size_t off = ((size_t)(cbase + cl_) * BC + i) * 1024 +
                           (lh * 32 + ln31) * 16 + 8 * h;
        wf[k] = *reinterpret_cast<const short8v*>(WbfC + off);
      }
    } else {
#pragma unroll
      for (int k = 0; k < 4; ++k) {
        const int cl_ = k >> 1, lh = k & 1;
        const float* src = W + ((size_t)(cbase + cl_) * BC + i) * 1024 +
                           (lh * 32 + ln31) * 16 + 8 * h;
        const float4 v0 = *reinterpret_cast<const float4*>(src);
        const float4 v1 = *reinterpret_cast<const float4*>(src + 4);
        wf[k] = cvt8(v0, v1);  // convert immediately (spill-proof)
      }
    }
#pragma unroll
    for (int k = 0; k < 4; ++k) asm volatile("" : "+v"(wf[k]));  // pin live
    if (PASS == 0) {
#pragma unroll
      for (int k = 0; k < 4; ++k) {
        const int cl_ = k >> 1, lh = k & 1;
        const size_t off = ((size_t)(cbase + cl_) * BC + i) * 1024 +
                           (lh * 32 + ln31) * 16 + 8 * h;
        *reinterpret_cast<short8v*>(WbfC + off) = wf[k];
      }
    }

    if (PASS == 1) {
      // ---- phase A (swapped): in-register l-sum ----
#pragma unroll
      for (int rowhalf = 0; rowhalf < 2; ++rowhalf) {
        ABfrag A;
        {
          const int r = rowhalf * 32 + ln31;
          A.h[0] = *reinterpret_cast<const short4v*>(&pbf[cap][r][8 * h]);
          A.h[1] = *reinterpret_cast<const short4v*>(&pbf[cap][r][8 * h + 4]);
        }
        const int b = (rowhalf * 32 + ln31) >> 4;
#pragma unroll
        for (int cl_ = 0; cl_ < 2; ++cl_) {
          float sc = 0.f;
#pragma unroll
          for (int lh = 0; lh < 2; ++lh) {
            const f32x16 acc = __builtin_amdgcn_mfma_f32_32x32x16_bf16(
                wf[cl_ * 2 + lh], A.v, zero16, 0, 0, 0);
            const float* mrow = &mu_s[b * CC + cbase + cl_][lh * 32 + 4 * h];
#pragma unroll
            for (int g = 0; g < 4; ++g) {
              const float4 m4 = *reinterpret_cast<const float4*>(mrow + 8 * g);
              float d;
              d = acc[4 * g + 0] - m4.x; sc = fmaf(d, d, sc);
              d = acc[4 * g + 1] - m4.y; sc = fmaf(d, d, sc);
              d = acc[4 * g + 2] - m4.z; sc = fmaf(d, d, sc);
              d = acc[4 * g + 3] - m4.w; sc = fmaf(d, d, sc);
            }
          }
          sc += __shfl_xor(sc, 32, 64);
          if (h == 0) sc_s[rowhalf * 32 + ln31][cbase + cl_] = sc;
        }
      }
      __syncthreads();
      // ---- softmax over c ----
      {
        const int r = t & 63, cq = t >> 6, b = r >> 4;
        float s[16];
#pragma unroll
        for (int cc = 0; cc < 16; ++cc) s[cc] = T_s[b * CC + cc] - sc_s[r][cc];
        float m = s[0];
#pragma unroll
        for (int cc = 1; cc < 16; ++cc) m = fmaxf(m, s[cc]);
        float den = 0.f;
#pragma unroll
        for (int cc = 0; cc < 16; ++cc) { s[cc] = __expf(s[cc] - m); den += s[cc]; }
        const float a = act_s[cap][r] / den;
#pragma unroll
        for (int k = 0; k < 2; ++k) {
          const int cc = 2 * cq + k;
          const float rh = fmaxf(s[cc] * a, 0.01f);
          rh2[cc][r] = rh;
          atomicAdd(&sr_s[b * CC + cc], rh);
        }
      }
      __syncthreads();
    }

    // ---- phase B: S1/S2 -> LDS accumulator ----
#pragma unroll
    for (int pair = 0; pair < 2; ++pair) {
      ABfrag A;
      {
        const int r = pair * 32 + ln31;
        A.h[0] = *reinterpret_cast<const short4v*>(&pbf[cap][r][8 * h]);
        A.h[1] = *reinterpret_cast<const short4v*>(&pbf[cap][r][8 * h + 4]);
      }
      float p1[4][2] = {}, p2[4][2] = {};
#pragma unroll
      for (int cl_ = 0; cl_ < 2; ++cl_) {
        float rq[16];
        if (PASS == 1) {
#pragma unroll
          for (int g = 0; g < 4; ++g) {
            const float4 v = *reinterpret_cast<const float4*>(
                &rh2[cbase + cl_][pair * 32 + 8 * g + 4 * h]);
            rq[4 * g + 0] = v.x; rq[4 * g + 1] = v.y;
            rq[4 * g + 2] = v.z; rq[4 * g + 3] = v.w;
          }
        } else {
#pragma unroll
          for (int g = 0; g < 4; ++g) {
            const float4 v = *reinterpret_cast<const float4*>(
                &act_s[cap][pair * 32 + 8 * g + 4 * h]);
            rq[4 * g + 0] = fmaxf(v.x * 0.0625f, 0.01f);
            rq[4 * g + 1] = fmaxf(v.y * 0.0625f, 0.01f);
            rq[4 * g + 2] = fmaxf(v.z * 0.0625f, 0.01f);
            rq[4 * g + 3] = fmaxf(v.w * 0.0625f, 0.01f);
          }
        }
#pragma unroll
        for (int lh = 0; lh < 2; ++lh) {
          const f32x16 acc = __builtin_amdgcn_mfma_f32_32x32x16_bf16(
              A.v, wf[cl_ * 2 + lh], zero16, 0, 0, 0);
          const int t4 = cl_ * 2 + lh;
#pragma unroll
          for (int j = 0; j < 16; ++j) {
            const float v = acc[j];
            const float rv = rq[j] * v;
            p1[t4][j >> 3] += rv;
            p2[t4][j >> 3] = fmaf(rv, v, p2[t4][j >> 3]);
          }
        }
      }
#pragma unroll
      for (int t4 = 0; t4 < 4; ++t4)
#pragma unroll
        for (int bh = 0; bh < 2; ++bh) {
          float v1 = p1[t4][bh]; v1 += __shfl_xor(v1, 32, 64);
          float v2 = p2[t4][bh]; v2 += __shfl_xor(v2, 32, 64);
          const int b = pair * 2 + bh, c = cbase + (t4 >> 1);
          const int idx = (b * CC + c) * LV + (t4 & 1) * 32 + ln31;
          if (h == 0) {
            if (cap == 0) { Sacc[idx] = v1; Sacc[SLAB + idx] = v2; }
            else          { Sacc[idx] += v1; Sacc[SLAB + idx] += v2; }
          }
        }
    }
  }

  // ---- Sr + slab store ----
  if (PASS == 1) {
    if (t < 64) Sacc[2 * SLAB + t] = sr_s[t];
  } else {
    if (t < 64) {
      const int b = t >> 4;
      float s = 0.f;
#pragma unroll
      for (int cp = 0; cp < 2; ++cp)
#pragma unroll
        for (int xy = 0; xy < 16; ++xy)
          s += fmaxf(act_s[cp][b * 16 + xy] * 0.0625f, 0.01f);
      Sacc[2 * SLAB + t] = s;
    }
  }
  __syncthreads();
  for (int idx = t; idx < SLABTOT; idx += 512) slab[idx] = Sacc[idx];
}

// ---- two-stage tree reduce, plain stores ----
__global__ void reduce_stageA(const float* __restrict__ Spart,
                              float* __restrict__ Spart2) {
  const int idx = blockIdx.x * 256 + threadIdx.x;
  if (idx >= SLABTOT) return;
  const float* base = Spart + (size_t)(blockIdx.y * 32) * SLABTOT + idx;
  float a = 0.f;
#pragma unroll 8
  for (int s = 0; s < 32; ++s) a += base[(size_t)s * SLABTOT];
  Spart2[(size_t)blockIdx.y * SLABTOT + idx] = a;
}

__global__ void reduce_stageB(const float* __restrict__ Spart2,
                              float* __restrict__ Sred, int nchunk) {
  const int idx = blockIdx.x * 256 + threadIdx.x;
  if (idx >= SLABTOT) return;
  float a = 0.f;
  for (int s = 0; s < nchunk; ++s) a += Spart2[(size_t)s * SLABTOT + idx];
  Sred[idx] = a;
}

// ---- final stats (512 threads) ----
__global__ void stats_final(const float* __restrict__ Sred,
                            const float* __restrict__ beta_v,
                            const float* __restrict__ beta_a,
                            const float* __restrict__ lam,
                            float* __restrict__ out) {
  __shared__ float lsum_s[64][8];
  const int t = threadIdx.x;
  const int bc = t >> 3, part = t & 7;
  const float inv = 1.f / Sred[2 * SLAB + bc];
  float lsl = 0.f;
#pragma unroll
  for (int q = 0; q < 8; ++q) {
    const int l = part * 8 + q;
    const int idx = bc * 64 + l;
    const float m = Sred[idx] * inv;
    const float s2 = fmaxf(Sred[SLAB + idx] * inv - m * m, 0.01f);
    lsl += logf(s2);
    out[(size_t)(bc >> 4) * 1040 + (bc & 15) * 64 + l] = m;
  }
  lsum_s[bc][part] = lsl;
  __syncthreads();
  if (t < 64) {
    float lsum = 0.f;
#pragma unroll
    for (int q = 0; q < 8; ++q) lsum += lsum_s[t][q];
    const float sr = Sred[2 * SLAB + t];
    const float z = lam[0] * (beta_a[t & 15] - (64.f * beta_v[0] + lsum) * sr);
    out[(size_t)(t >> 4) * 1040 + 1024 + (t & 15)] = 1.f / (1.f + expf(-z));
  }
}

// ===== legacy single-cap fallback (round-12 proven; small-ws only) =====
template <int PASS>
__global__ __launch_bounds__(512, 4) void em_sweep_legacy(
    const float* __restrict__ x, const float* __restrict__ W,
    const float* __restrict__ mu, const float* __restrict__ T,
    float* __restrict__ Spart, int nslab) {
  const int i = blockIdx.x, t = threadIdx.x;
  const int w = t >> 6, lane = t & 63;
  const int ln31 = lane & 31, h = lane >> 5;
  const int cbase = 2 * w;

  float* S1p = Spart + (size_t)(i % nslab) * SLABTOT;
  float* S2p = S1p + SLAB;
  float* Srp = S1p + 2 * SLAB;

  __shared__ __align__(16) unsigned short pbf[64][20];
  __shared__ float act_s[64];
  __shared__ float T_s[64];
  __shared__ float sr_s[64];
  __shared__ float sc_s[64][17];
  __shared__ float rh2[16][64];
  __shared__ __align__(16) float mu_s[64][64];

  short8v wf[4];
#pragma unroll
  for (int k = 0; k < 4; ++k) {
    const int cl_ = k >> 1, lh = k & 1;
    const float* src = W + ((size_t)(cbase + cl_) * BC + i) * 1024 +
                       (lh * 32 + ln31) * 16 + 8 * h;
    const float4 v0 = *reinterpret_cast<const float4*>(src);
    const float4 v1 = *reinterpret_cast<const float4*>(src + 4);
    wf[k] = cvt8(v0, v1);
  }
#pragma unroll
  for (int k = 0; k < 4; ++k) asm volatile("" : "+v"(wf[k]));

  if (t < 256) {
    const int b = t >> 6, p = (t >> 2) & 15, q = t & 3;
    const float4 v = *reinterpret_cast<const float4*>(
        x + ((size_t)(b * CH + p * BC + i)) * 16 + 4 * q);
    pbf[b * 16 + 4 * q + 0][p] = f2bf(v.x);
    pbf[b * 16 + 4 * q + 1][p] = f2bf(v.y);
    pbf[b * 16 + 4 * q + 2][p] = f2bf(v.z);
    pbf[b * 16 + 4 * q + 3][p] = f2bf(v.w);
  }
  if (t < 64) {
    const int b = t >> 4, xy = t & 15;
    act_s[t] = x[((size_t)(b * CH + PV * BC + i)) * 16 + xy];
    if (PASS == 1) { T_s[t] = T[t]; sr_s[t] = 0.f; }
  }
  if (PASS == 1) {
    const float4* msrc = reinterpret_cast<const float4*>(mu);
    float4* mdst = reinterpret_cast<float4*>(&mu_s[0][0]);
    mdst[t] = msrc[t];
    mdst[t + 512] = msrc[t + 512];
  }
  __syncthreads();

  const f32x16 zero16 = {};

  if (PASS == 1) {
#pragma unroll
    for (int rowhalf = 0; rowhalf < 2; ++rowhalf) {
      ABfrag A;
      {
        const int r = rowhalf * 32 + ln31;
        A.h[0] = *reinterpret_cast<const short4v*>(&pbf[r][8 * h]);
        A.h[1] = *reinterpret_cast<const short4v*>(&pbf[r][8 * h + 4]);
      }
      const int b = (rowhalf * 32 + ln31) >> 4;
#pragma unroll
      for (int cl_ = 0; cl_ < 2; ++cl_) {
        float sc = 0.f;
#pragma unroll
        for (int lh = 0; lh < 2; ++lh) {
          const f32x16 acc = __builtin_amdgcn_mfma_f32_32x32x16_bf16(
              wf[cl_ * 2 + lh], A.v, zero16, 0, 0, 0);
          const float* mrow = &mu_s[b * CC + cbase + cl_][lh * 32 + 4 * h];
#pragma unroll
          for (int g = 0; g < 4; ++g) {
            const float4 m4 = *reinterpret_cast<const float4*>(mrow + 8 * g);
            float d;
            d = acc[4 * g + 0] - m4.x; sc = fmaf(d, d, sc);
            d = acc[4 * g + 1] - m4.y; sc = fmaf(d, d, sc);
            d = acc[4 * g + 2] - m4.z; sc = fmaf(d, d, sc);
            d = acc[4 * g + 3] - m4.w; sc = fmaf(d, d, sc);
          }
        }
        sc += __shfl_xor(sc, 32, 64);
        if (h == 0) sc_s[rowhalf * 32 + ln31][cbase + cl_] = sc;
      }
    }
    __syncthreads();
    {
      const int r = t & 63, cq = t >> 6, b = r >> 4;
      float s[16];
#pragma unroll
      for (int cc = 0; cc < 16; ++cc) s[cc] = T_s[b * CC + cc] - sc_s[r][cc];
      float m = s[0];
#pragma unroll
      for (int cc = 1; cc < 16; ++cc) m = fmaxf(m, s[cc]);
      float den = 0.f;
#pragma unroll
      for (int cc = 0; cc < 16; ++cc) { s[cc] = __expf(s[cc] - m); den += s[cc]; }
      const float a = act_s[r] / den;
#pragma unroll
      for (int k = 0; k < 2; ++k) {
        const int cc = 2 * cq + k;
        const float rh = fmaxf(s[cc] * a, 0.01f);
        rh2[cc][r] = rh;
        atomicAdd(&sr_s[b * CC + cc], rh);
      }
    }
    __syncthreads();
  }

#pragma unroll
  for (int pair = 0; pair < 2; ++pair) {
    ABfrag A;
    {
      const int r = pair * 32 + ln31;
      A.h[0] = *reinterpret_cast<const short4v*>(&pbf[r][8 * h]);
      A.h[1] = *reinterpret_cast<const short4v*>(&pbf[r][8 * h + 4]);
    }
    float p1[4][2] = {}, p2[4][2] = {};
#pragma unroll
    for (int cl_ = 0; cl_ < 2; ++cl_) {
      float rq[16];
      if (PASS == 1) {
#pragma unroll
        for (int g = 0; g < 4; ++g) {
          const float4 v = *reinterpret_cast<const float4*>(
              &rh2[cbase + cl_][pair * 32 + 8 * g + 4 * h]);
          rq[4 * g + 0] = v.x; rq[4 * g + 1] = v.y;
          rq[4 * g + 2] = v.z; rq[4 * g + 3] = v.w;
        }
      } else {
#pragma unroll
        for (int g = 0; g < 4; ++g) {
          const float4 v = *reinterpret_cast<const float4*>(
              &act_s[pair * 32 + 8 * g + 4 * h]);
          rq[4 * g + 0] = fmaxf(v.x * 0.0625f, 0.01f);
          rq[4 * g + 1] = fmaxf(v.y * 0.0625f, 0.01f);
          rq[4 * g + 2] = fmaxf(v.z * 0.0625f, 0.01f);
          rq[4 * g + 3] = fmaxf(v.w * 0.0625f, 0.01f);
        }
      }
#pragma unroll
      for (int lh = 0; lh < 2; ++lh) {
        const f32x16 acc = __builtin_amdgcn_mfma_f32_32x32x16_bf16(
            A.v, wf[cl_ * 2 + lh], zero16, 0, 0, 0);
        const int t4 = cl_ * 2 + lh;
#pragma unroll
        for (int j = 0; j < 16; ++j) {
          const float v = acc[j];
          const float rv = rq[j] * v;
          p1[t4][j >> 3] += rv;
          p2[t4][j >> 3] = fmaf(rv, v, p2[t4][j >> 3]);
        }
      }
    }
#pragma unroll
    for (int t4 = 0; t4 < 4; ++t4)
#pragma unroll
      for (int bh = 0; bh < 2; ++bh) {
        float v1 = p1[t4][bh]; v1 += __shfl_xor(v1, 32, 64);
        float v2 = p2[t4][bh]; v2 += __shfl_xor(v2, 32, 64);
        const int b = pair * 2 + bh, c = cbase + (t4 >> 1);
        const int idx = (b * CC + c) * LV + (t4 & 1) * 32 + ln31;
        if (h == 0) { atomicAdd(&S1p[idx], v1); atomicAdd(&S2p[idx], v2); }
      }
  }

  if (PASS == 1) {
    if (t < 64) atomicAdd(&Srp[t], sr_s[t]);
  } else {
    if (t < 64) {
      const int b = t >> 4;
      float s = 0.f;
#pragma unroll
      for (int xy = 0; xy < 16; ++xy) s += fmaxf(act_s[b * 16 + xy] * 0.0625f, 0.01f);
      atomicAdd(&Srp[t], s);
    }
  }
}

__global__ void reduce_slabs(const float* __restrict__ Spart, float* __restrict__ Sred,
                             int nslab, int chunk) {
  const int idx = blockIdx.x * 256 + threadIdx.x;
  if (idx >= SLABTOT) return;
  const int s0 = blockIdx.y * chunk;
  const int s1 = min(s0 + chunk, nslab);
  float a = 0.f;
#pragma unroll 8
  for (int s = s0; s < s1; s++) a += Spart[(size_t)s * SLABTOT + idx];
  atomicAdd(&Sred[idx], a);
}

template <int FINAL>
__global__ void stats_post(const float* __restrict__ Sred,
                           const float* __restrict__ beta_v,
                           const float* __restrict__ beta_a,
                           const float* __restrict__ lam,
                           float* __restrict__ mu_out, float* __restrict__ T_out,
                           float* __restrict__ out) {
  __shared__ float lsum_s[64][8];
  const int t = threadIdx.x;
  const int bc = t >> 3, part = t & 7;
  const float inv = 1.f / Sred[2 * SLAB + bc];
  float lsl = 0.f;
#pragma unroll
  for (int q = 0; q < 8; ++q) {
    const int l = part * 8 + q;
    const int idx = bc * 64 + l;
    const float m = Sred[idx] * inv;
    const float s2 = fmaxf(Sred[SLAB + idx] * inv - m * m, 0.01f);
    lsl += logf(s2);
    if (FINAL) out[(size_t)(bc >> 4) * 1040 + (bc & 15) * 64 + l] = m;
    else mu_out[idx] = m;
  }
  lsum_s[bc][part] = lsl;
  __syncthreads();
  if (t < 64) {
    float lsum = 0.f;
#pragma unroll
    for (int q = 0; q < 8; ++q) lsum += lsum_s[t][q];
    const float sr = Sred[2 * SLAB + t];
    const float z = lam[0] * (beta_a[t & 15] - (64.f * beta_v[0] + lsum) * sr);
    const float ac = 1.f / (1.f + expf(-z));
    if (FINAL) out[(size_t)(t >> 4) * 1040 + 1024 + (t & 15)] = ac;
    else T_out[t] = logf(ac) - 0.5f * (64.f * LOG_2PI_F + lsum);
  }
}

extern "C" void kernel_launch(void* const* d_in, const int* in_sizes, int n_in,
                              void* d_out, int out_size, void* d_ws, size_t ws_size,
                              hipStream_t stream) {
  const float* x = (const float*)d_in[0];
  const float* W = (const float*)d_in[1];
  const float* beta_v = (const float*)d_in[2];
  const float* beta_a = (const float*)d_in[3];
  const float* lam = (const float*)d_in[4];
  float* out = (float*)d_out;

  // cache-path layout: Spart(512 slabs) | Sred | WbfC | poseC | actC | Spart2(16)
  const size_t need_cache =
      ((size_t)NB2 * SLABTOT + SLABTOT) * sizeof(float) + WBF_ELEMS * 2 +
      POSE_ELEMS * 2 + ACT_ELEMS * sizeof(float) +
      (size_t)16 * SLABTOT * sizeof(float);

  float* Spart = (float*)d_ws;

  if (ws_size >= need_cache) {
    float* Sred = Spart + (size_t)NB2 * SLABTOT;
    unsigned short* WbfC = (unsigned short*)(Sred + SLABTOT);
    unsigned short* poseC = WbfC + WBF_ELEMS;
    float* actC = (float*)(poseC + POSE_ELEMS);
    float* Spart2 = actC + ACT_ELEMS;

    const dim3 agrid((SLABTOT + 255) / 256, 16);  // 512 slabs / 32
    const dim3 bgrid((SLABTOT + 255) / 256);
    // ---- pass 0 ----
    em_sweep2<0><<<dim3(NB2), dim3(512), 0, stream>>>(
        x, W, nullptr, beta_v, beta_a, lam, Spart, WbfC, poseC, actC);
    reduce_stageA<<<agrid, dim3(256), 0, stream>>>(Spart, Spart2);
    reduce_stageB<<<bgrid, dim3(256), 0, stream>>>(Spart2, Sred, 16);
    // ---- pass 1 (mu/T computed in-block from Sred) ----
    em_sweep2<1><<<dim3(NB2), dim3(512), 0, stream>>>(
        x, W, Sred, beta_v, beta_a, lam, Spart, WbfC, poseC, actC);
    reduce_stageA<<<agrid, dim3(256), 0, stream>>>(Spart, Spart2);
    reduce_stageB<<<bgrid, dim3(256), 0, stream>>>(Spart2, Sred, 16);
    stats_final<<<dim3(1), dim3(512), 0, stream>>>(Sred, beta_v, beta_a, lam, out);
    return;
  }

  // ---- fallback: legacy memset + atomic reduce (32 slabs, 1024 blocks) ----
  const int nslab = NSLAB_SM;
  float* Sred = Spart + (size_t)nslab * SLABTOT;
  float* muW = Sred + SLABTOT;
  float* Tw = muW + SLAB;
  const int chunk = 32;
  const dim3 rgrid((SLABTOT + 255) / 256, (nslab + chunk - 1) / chunk);

  hipMemsetAsync(Spart, 0, (size_t)nslab * SLABTOT * sizeof(float), stream);
  hipMemsetAsync(Sred, 0, SLABTOT * sizeof(float), stream);
  em_sweep_legacy<0><<<dim3(BC), dim3(512), 0, stream>>>(x, W, nullptr, nullptr, Spart, nslab);
  reduce_slabs<<<rgrid, dim3(256), 0, stream>>>(Spart, Sred, nslab, chunk);
  stats_post<0><<<dim3(1), dim3(512), 0, stream>>>(Sred, beta_v, beta_a, lam, muW, Tw, nullptr);

  hipMemsetAsync(Spart, 0, (size_t)nslab * SLABTOT * sizeof(float), stream);
  em_sweep_legacy<1><<<dim3(BC), dim3(512), 0, stream>>>(x, W, muW, Tw, Spart, nslab);
  hipMemsetAsync(Sred, 0, SLABTOT * sizeof(float), stream);
  reduce_slabs<<<rgrid, dim3(256), 0, stream>>>(Spart, Sred, nslab, chunk);
  stats_post<1><<<dim3(1), dim3(512), 0, stream>>>(Sred, beta_v, beta_a, lam, nullptr, nullptr, out);
}

// Round 19
// 78.856 us; speedup vs baseline: 1.0622x; 1.0231x over previous
//
#include <hip/hip_runtime.h>

#define LOG_2PI_F 1.8378770664093453f

constexpr int BC = 1024, CC = 16, PV = 16, LV = 64, BB = 4;
constexpr int CH = (PV + 1) * BC;
constexpr int SLAB = BB * CC * LV;           // 4096
constexpr int SLABTOT = 2 * SLAB + BB * CC;  // 8256
constexpr int NB2 = 512;                     // 2-cap grid
constexpr int NSLAB_SM = 32;
constexpr size_t WBF_ELEMS = (size_t)CC * BC * LV * PV;   // 16.7M shorts
constexpr size_t POSE_ELEMS = (size_t)BC * 64 * 16;       // shorts
constexpr size_t ACT_ELEMS = (size_t)BC * 64;             // floats

typedef __attribute__((ext_vector_type(4))) short short4v;
typedef __attribute__((ext_vector_type(8))) short short8v;
typedef __attribute__((ext_vector_type(16))) float f32x16;

union ABfrag { short8v v; short4v h[2]; unsigned short u[8]; };

__device__ __forceinline__ unsigned short f2bf(float f) {
  unsigned u = __float_as_uint(f);
  u += 0x7fffu + ((u >> 16) & 1u);  // RNE
  return (unsigned short)(u >> 16);
}

__device__ __forceinline__ short8v cvt8(const float4 a, const float4 b) {
  ABfrag f;
  f.u[0] = f2bf(a.x); f.u[1] = f2bf(a.y); f.u[2] = f2bf(a.z); f.u[3] = f2bf(a.w);
  f.u[4] = f2bf(b.x); f.u[5] = f2bf(b.y); f.u[6] = f2bf(b.z); f.u[7] = f2bf(b.w);
  return f.v;
}

// ===== 2-caps-per-block sweep (512 thr / 8 waves / 2c per wave, grid 512) =====
// PASS1 RESTRUCTURE (round 19): barrier-batched phases -- [A0,A1, bar,
// softmax(both), bar, B0,B1] instead of 4-barrier per-cap interleave. The two
// caps' independent load+MFMA streams issue back-to-back (natural overlap);
// wf reloaded per phase from bf16 cache (dead between phases -> no spill;
// rounds 8/9/13 lesson: never hold register state across compute regions).
// sc_s/rh2 are per-cap (+8.3KB LDS, total ~74.5KB, still 2 blocks/CU).
// Cross-cap S1/S2 accumulate in LDS Sacc. PASS0 (phase B only) unchanged.
// MFMA v_mfma_f32_32x32x16_bf16: A m=lane&31,k=8h+j ;
// C/D col=lane&31,row=(reg&3)+8*(reg>>2)+4*h [m74/m101].
// Phase A: SWAPPED mfma(W,pose) -> l-sum in-register + 1 shfl_xor(32).
// Phase B: mfma(pose,W), r-sum in-register, h==0 lanes write/add Sacc.
// PASS1 computes mu_s/T_s in-block from Sred (33KB broadcast, L2-resident).
template <int PASS>
__global__ __launch_bounds__(512, 4) void em_sweep2(
    const float* __restrict__ x, const float* __restrict__ W,
    const float* __restrict__ SredIn, const float* __restrict__ beta_v,
    const float* __restrict__ beta_a, const float* __restrict__ lam,
    float* __restrict__ Spart,
    unsigned short* __restrict__ WbfC, unsigned short* __restrict__ poseC,
    float* __restrict__ actC) {
  const int bid = blockIdx.x, t = threadIdx.x;
  const int w = t >> 6, lane = t & 63;
  const int ln31 = lane & 31, h = lane >> 5;
  const int cbase = 2 * w;

  float* slab = Spart + (size_t)bid * SLABTOT;

  __shared__ __align__(16) unsigned short pbf[2][64][20];  // pitch 40B
  __shared__ float act_s[2][64];
  __shared__ float T_s[64];
  __shared__ float sr_s[64];
  __shared__ float sc_s[2][64][17];
  __shared__ __align__(16) float rh2[2][16][64];
  __shared__ __align__(16) float mu_s[64][64];
  __shared__ float lsum_s[64][8];
  __shared__ float Sacc[SLABTOT];  // cross-cap accumulator (LDS, not regs!)

  const f32x16 zero16 = {};

  if (PASS == 1) {
    // ---- prologue: stage pose/act, mu/T from Sred ----
    if (t < 256) {  // pose from bf16 cache, clean 16B chunks
      const int cap = t >> 7, tt = t & 127;
      const int r = tt >> 1, half = tt & 1;
      const int i = bid + cap * NB2;
      const int4 v = *reinterpret_cast<const int4*>(
          poseC + ((size_t)i * 64 + r) * 16 + 8 * half);
      union { int4 q; short4v s[2]; } u;
      u.q = v;
      *reinterpret_cast<short4v*>(&pbf[cap][r][8 * half]) = u.s[0];
      *reinterpret_cast<short4v*>(&pbf[cap][r][8 * half + 4]) = u.s[1];
    }
    if (t < 128) {
      const int cap = t >> 6, r = t & 63;
      act_s[cap][r] = actC[(size_t)(bid + cap * NB2) * 64 + r];
    }
    if (t < 64) sr_s[t] = 0.f;
    {
      const int bc = t >> 3, part = t & 7;
      const float inv = 1.f / SredIn[2 * SLAB + bc];
      float lsl = 0.f;
#pragma unroll
      for (int q = 0; q < 8; ++q) {
        const int idx = bc * 64 + part * 8 + q;
        const float m = SredIn[idx] * inv;
        const float s2 = fmaxf(SredIn[SLAB + idx] * inv - m * m, 0.01f);
        lsl += logf(s2);
        mu_s[bc][part * 8 + q] = m;
      }
      lsum_s[bc][part] = lsl;
    }
    __syncthreads();
    if (t < 64) {
      float lsum = 0.f;
#pragma unroll
      for (int q = 0; q < 8; ++q) lsum += lsum_s[t][q];
      const float sr = SredIn[2 * SLAB + t];
      const float z = lam[0] * (beta_a[t & 15] - (64.f * beta_v[0] + lsum) * sr);
      const float ac = 1.f / (1.f + expf(-z));
      T_s[t] = logf(ac) - 0.5f * (64.f * LOG_2PI_F + lsum);
    }
    __syncthreads();

    // ---- phase A for BOTH caps (back-to-back, no barrier between) ----
#pragma unroll
    for (int cap = 0; cap < 2; ++cap) {
      const int i = bid + cap * NB2;
      short8v wf[4];
#pragma unroll
      for (int k = 0; k < 4; ++k) {
        const int cl_ = k >> 1, lh = k & 1;
        const size_t off = ((size_t)(cbase + cl_) * BC + i) * 1024 +
                           (lh * 32 + ln31) * 16 + 8 * h;
        wf[k] = *reinterpret_cast<const short8v*>(WbfC + off);
      }
#pragma unroll
      for (int rowhalf = 0; rowhalf < 2; ++rowhalf) {
        ABfrag A;
        {
          const int r = rowhalf * 32 + ln31;
          A.h[0] = *reinterpret_cast<const short4v*>(&pbf[cap][r][8 * h]);
          A.h[1] = *reinterpret_cast<const short4v*>(&pbf[cap][r][8 * h + 4]);
        }
        const int b = (rowhalf * 32 + ln31) >> 4;
#pragma unroll
        for (int cl_ = 0; cl_ < 2; ++cl_) {
          float sc = 0.f;
#pragma unroll
          for (int lh = 0; lh < 2; ++lh) {
            const f32x16 acc = __builtin_amdgcn_mfma_f32_32x32x16_bf16(
                wf[cl_ * 2 + lh], A.v, zero16, 0, 0, 0);
            const float* mrow = &mu_s[b * CC + cbase + cl_][lh * 32 + 4 * h];
#pragma unroll
            for (int g = 0; g < 4; ++g) {
              const float4 m4 = *reinterpret_cast<const float4*>(mrow + 8 * g);
              float d;
              d = acc[4 * g + 0] - m4.x; sc = fmaf(d, d, sc);
              d = acc[4 * g + 1] - m4.y; sc = fmaf(d, d, sc);
              d = acc[4 * g + 2] - m4.z; sc = fmaf(d, d, sc);
              d = acc[4 * g + 3] - m4.w; sc = fmaf(d, d, sc);
            }
          }
          sc += __shfl_xor(sc, 32, 64);
          if (h == 0) sc_s[cap][rowhalf * 32 + ln31][cbase + cl_] = sc;
        }
      }
    }
    __syncthreads();

    // ---- softmax over c, both caps ----
#pragma unroll
    for (int cap = 0; cap < 2; ++cap) {
      const int r = t & 63, cq = t >> 6, b = r >> 4;
      float s[16];
#pragma unroll
      for (int cc = 0; cc < 16; ++cc) s[cc] = T_s[b * CC + cc] - sc_s[cap][r][cc];
      float m = s[0];
#pragma unroll
      for (int cc = 1; cc < 16; ++cc) m = fmaxf(m, s[cc]);
      float den = 0.f;
#pragma unroll
      for (int cc = 0; cc < 16; ++cc) { s[cc] = __expf(s[cc] - m); den += s[cc]; }
      const float a = act_s[cap][r] / den;
#pragma unroll
      for (int k = 0; k < 2; ++k) {
        const int cc = 2 * cq + k;
        const float rh = fmaxf(s[cc] * a, 0.01f);
        rh2[cap][cc][r] = rh;
        atomicAdd(&sr_s[b * CC + cc], rh);
      }
    }
    __syncthreads();

    // ---- phase B for BOTH caps (back-to-back) ----
#pragma unroll
    for (int cap = 0; cap < 2; ++cap) {
      const int i = bid + cap * NB2;
      short8v wf[4];
#pragma unroll
      for (int k = 0; k < 4; ++k) {
        const int cl_ = k >> 1, lh = k & 1;
        const size_t off = ((size_t)(cbase + cl_) * BC + i) * 1024 +
                           (lh * 32 + ln31) * 16 + 8 * h;
        wf[k] = *reinterpret_cast<const short8v*>(WbfC + off);
      }
#pragma unroll
      for (int pair = 0; pair < 2; ++pair) {
        ABfrag A;
        {
          const int r = pair * 32 + ln31;
          A.h[0] = *reinterpret_cast<const short4v*>(&pbf[cap][r][8 * h]);
          A.h[1] = *reinterpret_cast<const short4v*>(&pbf[cap][r][8 * h + 4]);
        }
        float p1[4][2] = {}, p2[4][2] = {};
#pragma unroll
        for (int cl_ = 0; cl_ < 2; ++cl_) {
          float rq[16];
#pragma unroll
          for (int g = 0; g < 4; ++g) {
            const float4 v = *reinterpret_cast<const float4*>(
                &rh2[cap][cbase + cl_][pair * 32 + 8 * g + 4 * h]);
            rq[4 * g + 0] = v.x; rq[4 * g + 1] = v.y;
            rq[4 * g + 2] = v.z; rq[4 * g + 3] = v.w;
          }
#pragma unroll
          for (int lh = 0; lh < 2; ++lh) {
            const f32x16 acc = __builtin_amdgcn_mfma_f32_32x32x16_bf16(
                A.v, wf[cl_ * 2 + lh], zero16, 0, 0, 0);
            const int t4 = cl_ * 2 + lh;
#pragma unroll
            for (int j = 0; j < 16; ++j) {
              const float v = acc[j];
              const float rv = rq[j] * v;
              p1[t4][j >> 3] += rv;
              p2[t4][j >> 3] = fmaf(rv, v, p2[t4][j >> 3]);
            }
          }
        }
#pragma unroll
        for (int t4 = 0; t4 < 4; ++t4)
#pragma unroll
          for (int bh = 0; bh < 2; ++bh) {
            float v1 = p1[t4][bh]; v1 += __shfl_xor(v1, 32, 64);
            float v2 = p2[t4][bh]; v2 += __shfl_xor(v2, 32, 64);
            const int b = pair * 2 + bh, c = cbase + (t4 >> 1);
            const int idx = (b * CC + c) * LV + (t4 & 1) * 32 + ln31;
            if (h == 0) {
              if (cap == 0) { Sacc[idx] = v1; Sacc[SLAB + idx] = v2; }
              else          { Sacc[idx] += v1; Sacc[SLAB + idx] += v2; }
            }
          }
      }
    }
    if (t < 64) Sacc[2 * SLAB + t] = sr_s[t];
  } else {
    // ================= PASS 0 (unchanged round-15 structure) =================
    {
      const int cap = t >> 8, tt = t & 255;
      const int b = tt >> 6, p = (tt >> 2) & 15, q = tt & 3;
      const int i = bid + cap * NB2;
      const float4 v = *reinterpret_cast<const float4*>(
          x + ((size_t)(b * CH + p * BC + i)) * 16 + 4 * q);
      pbf[cap][b * 16 + 4 * q + 0][p] = f2bf(v.x);
      pbf[cap][b * 16 + 4 * q + 1][p] = f2bf(v.y);
      pbf[cap][b * 16 + 4 * q + 2][p] = f2bf(v.z);
      pbf[cap][b * 16 + 4 * q + 3][p] = f2bf(v.w);
    }
    if (t < 128) {
      const int cap = t >> 6, r = t & 63;
      const int b = r >> 4, xy = r & 15;
      const float a = x[((size_t)(b * CH + PV * BC + bid + cap * NB2)) * 16 + xy];
      act_s[cap][r] = a;
      actC[(size_t)(bid + cap * NB2) * 64 + r] = a;
    }
    __syncthreads();
    // persist pose-bf16 (reads LDS after barrier)
    if (t < 256) {
      const int cap = t >> 7, tt = t & 127;
      const int r = tt >> 1, half = tt & 1;
      const int i = bid + cap * NB2;
      union { int4 q; short4v s[2]; } u;
      u.s[0] = *reinterpret_cast<const short4v*>(&pbf[cap][r][8 * half]);
      u.s[1] = *reinterpret_cast<const short4v*>(&pbf[cap][r][8 * half + 4]);
      *reinterpret_cast<int4*>(poseC + ((size_t)i * 64 + r) * 16 + 8 * half) = u.q;
    }

#pragma unroll
    for (int cap = 0; cap < 2; ++cap) {
      const int i = bid + cap * NB2;
      short8v wf[4];
#pragma unroll
      for (int k = 0; k < 4; ++k) {
        const int cl_ = k >> 1, lh = k & 1;
        const float* src = W + ((size_t)(cbase + cl_) * BC + i) * 1024 +
                           (lh * 32 + ln31) * 16 + 8 * h;
        const float4 v0 = *reinterpret_cast<const float4*>(src);
        const float4 v1 = *reinterpret_cast<const float4*>(src + 4);
        wf[k] = cvt8(v0, v1);  // convert immediately (spill-proof)
      }
#pragma unroll
      for (int k = 0; k < 4; ++k) asm volatile("" : "+v"(wf[k]));  // pin live
#pragma unroll
      for (int k = 0; k < 4; ++k) {
        const int cl_ = k >> 1, lh = k & 1;
        const size_t off = ((size_t)(cbase + cl_) * BC + i) * 1024 +
                           (lh * 32 + ln31) * 16 + 8 * h;
        *reinterpret_cast<short8v*>(WbfC + off) = wf[k];
      }

#pragma unroll
      for (int pair = 0; pair < 2; ++pair) {
        ABfrag A;
        {
          const int r = pair * 32 + ln31;
          A.h[0] = *reinterpret_cast<const short4v*>(&pbf[cap][r][8 * h]);
          A.h[1] = *reinterpret_cast<const short4v*>(&pbf[cap][r][8 * h + 4]);
        }
        float p1[4][2] = {}, p2[4][2] = {};
#pragma unroll
        for (int cl_ = 0; cl_ < 2; ++cl_) {
          float rq[16];
#pragma unroll
          for (int g = 0; g < 4; ++g) {
            const float4 v = *reinterpret_cast<const float4*>(
                &act_s[cap][pair * 32 + 8 * g + 4 * h]);
            rq[4 * g + 0] = fmaxf(v.x * 0.0625f, 0.01f);
            rq[4 * g + 1] = fmaxf(v.y * 0.0625f, 0.01f);
            rq[4 * g + 2] = fmaxf(v.z * 0.0625f, 0.01f);
            rq[4 * g + 3] = fmaxf(v.w * 0.0625f, 0.01f);
          }
#pragma unroll
          for (int lh = 0; lh < 2; ++lh) {
            const f32x16 acc = __builtin_amdgcn_mfma_f32_32x32x16_bf16(
                A.v, wf[cl_ * 2 + lh], zero16, 0, 0, 0);
            const int t4 = cl_ * 2 + lh;
#pragma unroll
            for (int j = 0; j < 16; ++j) {
              const float v = acc[j];
              const float rv = rq[j] * v;
              p1[t4][j >> 3] += rv;
              p2[t4][j >> 3] = fmaf(rv, v, p2[t4][j >> 3]);
            }
          }
        }
#pragma unroll
        for (int t4 = 0; t4 < 4; ++t4)
#pragma unroll
          for (int bh = 0; bh < 2; ++bh) {
            float v1 = p1[t4][bh]; v1 += __shfl_xor(v1, 32, 64);
            float v2 = p2[t4][bh]; v2 += __shfl_xor(v2, 32, 64);
            const int b = pair * 2 + bh, c = cbase + (t4 >> 1);
            const int idx = (b * CC + c) * LV + (t4 & 1) * 32 + ln31;
            if (h == 0) {
              if (cap == 0) { Sacc[idx] = v1; Sacc[SLAB + idx] = v2; }
              else          { Sacc[idx] += v1; Sacc[SLAB + idx] += v2; }
            }
          }
      }
    }
    if (t < 64) {
      const int b = t >> 4;
      float s = 0.f;
#pragma unroll
      for (int cp = 0; cp < 2; ++cp)
#pragma unroll
        for (int xy = 0; xy < 16; ++xy)
          s += fmaxf(act_s[cp][b * 16 + xy] * 0.0625f, 0.01f);
      Sacc[2 * SLAB + t] = s;
    }
  }

  __syncthreads();
  for (int idx = t; idx < SLABTOT; idx += 512) slab[idx] = Sacc[idx];
}

// ---- two-stage tree reduce, plain stores ----
__global__ void reduce_stageA(const float* __restrict__ Spart,
                              float* __restrict__ Spart2) {
  const int idx = blockIdx.x * 256 + threadIdx.x;
  if (idx >= SLABTOT) return;
  const float* base = Spart + (size_t)(blockIdx.y * 32) * SLABTOT + idx;
  float a = 0.f;
#pragma unroll 8
  for (int s = 0; s < 32; ++s) a += base[(size_t)s * SLABTOT];
  Spart2[(size_t)blockIdx.y * SLABTOT + idx] = a;
}

__global__ void reduce_stageB(const float* __restrict__ Spart2,
                              float* __restrict__ Sred, int nchunk) {
  const int idx = blockIdx.x * 256 + threadIdx.x;
  if (idx >= SLABTOT) return;
  float a = 0.f;
  for (int s = 0; s < nchunk; ++s) a += Spart2[(size_t)s * SLABTOT + idx];
  Sred[idx] = a;
}

// ---- final stats (512 threads) ----
__global__ void stats_final(const float* __restrict__ Sred,
                            const float* __restrict__ beta_v,
                            const float* __restrict__ beta_a,
                            const float* __restrict__ lam,
                            float* __restrict__ out) {
  __shared__ float lsum_s[64][8];
  const int t = threadIdx.x;
  const int bc = t >> 3, part = t & 7;
  const float inv = 1.f / Sred[2 * SLAB + bc];
  float lsl = 0.f;
#pragma unroll
  for (int q = 0; q < 8; ++q) {
    const int l = part * 8 + q;
    const int idx = bc * 64 + l;
    const float m = Sred[idx] * inv;
    const float s2 = fmaxf(Sred[SLAB + idx] * inv - m * m, 0.01f);
    lsl += logf(s2);
    out[(size_t)(bc >> 4) * 1040 + (bc & 15) * 64 + l] = m;
  }
  lsum_s[bc][part] = lsl;
  __syncthreads();
  if (t < 64) {
    float lsum = 0.f;
#pragma unroll
    for (int q = 0; q < 8; ++q) lsum += lsum_s[t][q];
    const float sr = Sred[2 * SLAB + t];
    const float z = lam[0] * (beta_a[t & 15] - (64.f * beta_v[0] + lsum) * sr);
    out[(size_t)(t >> 4) * 1040 + 1024 + (t & 15)] = 1.f / (1.f + expf(-z));
  }
}

// ===== legacy single-cap fallback (round-12 proven; small-ws only) =====
template <int PASS>
__global__ __launch_bounds__(512, 4) void em_sweep_legacy(
    const float* __restrict__ x, const float* __restrict__ W,
    const float* __restrict__ mu, const float* __restrict__ T,
    float* __restrict__ Spart, int nslab) {
  const int i = blockIdx.x, t = threadIdx.x;
  const int w = t >> 6, lane = t & 63;
  const int ln31 = lane & 31, h = lane >> 5;
  const int cbase = 2 * w;

  float* S1p = Spart + (size_t)(i % nslab) * SLABTOT;
  float* S2p = S1p + SLAB;
  float* Srp = S1p + 2 * SLAB;

  __shared__ __align__(16) unsigned short pbf[64][20];
  __shared__ float act_s[64];
  __shared__ float T_s[64];
  __shared__ float sr_s[64];
  __shared__ float sc_s[64][17];
  __shared__ float rh2[16][64];
  __shared__ __align__(16) float mu_s[64][64];

  short8v wf[4];
#pragma unroll
  for (int k = 0; k < 4; ++k) {
    const int cl_ = k >> 1, lh = k & 1;
    const float* src = W + ((size_t)(cbase + cl_) * BC + i) * 1024 +
                       (lh * 32 + ln31) * 16 + 8 * h;
    const float4 v0 = *reinterpret_cast<const float4*>(src);
    const float4 v1 = *reinterpret_cast<const float4*>(src + 4);
    wf[k] = cvt8(v0, v1);
  }
#pragma unroll
  for (int k = 0; k < 4; ++k) asm volatile("" : "+v"(wf[k]));

  if (t < 256) {
    const int b = t >> 6, p = (t >> 2) & 15, q = t & 3;
    const float4 v = *reinterpret_cast<const float4*>(
        x + ((size_t)(b * CH + p * BC + i)) * 16 + 4 * q);
    pbf[b * 16 + 4 * q + 0][p] = f2bf(v.x);
    pbf[b * 16 + 4 * q + 1][p] = f2bf(v.y);
    pbf[b * 16 + 4 * q + 2][p] = f2bf(v.z);
    pbf[b * 16 + 4 * q + 3][p] = f2bf(v.w);
  }
  if (t < 64) {
    const int b = t >> 4, xy = t & 15;
    act_s[t] = x[((size_t)(b * CH + PV * BC + i)) * 16 + xy];
    if (PASS == 1) { T_s[t] = T[t]; sr_s[t] = 0.f; }
  }
  if (PASS == 1) {
    const float4* msrc = reinterpret_cast<const float4*>(mu);
    float4* mdst = reinterpret_cast<float4*>(&mu_s[0][0]);
    mdst[t] = msrc[t];
    mdst[t + 512] = msrc[t + 512];
  }
  __syncthreads();

  const f32x16 zero16 = {};

  if (PASS == 1) {
#pragma unroll
    for (int rowhalf = 0; rowhalf < 2; ++rowhalf) {
      ABfrag A;
      {
        const int r = rowhalf * 32 + ln31;
        A.h[0] = *reinterpret_cast<const short4v*>(&pbf[r][8 * h]);
        A.h[1] = *reinterpret_cast<const short4v*>(&pbf[r][8 * h + 4]);
      }
      const int b = (rowhalf * 32 + ln31) >> 4;
#pragma unroll
      for (int cl_ = 0; cl_ < 2; ++cl_) {
        float sc = 0.f;
#pragma unroll
        for (int lh = 0; lh < 2; ++lh) {
          const f32x16 acc = __builtin_amdgcn_mfma_f32_32x32x16_bf16(
              wf[cl_ * 2 + lh], A.v, zero16, 0, 0, 0);
          const float* mrow = &mu_s[b * CC + cbase + cl_][lh * 32 + 4 * h];
#pragma unroll
          for (int g = 0; g < 4; ++g) {
            const float4 m4 = *reinterpret_cast<const float4*>(mrow + 8 * g);
            float d;
            d = acc[4 * g + 0] - m4.x; sc = fmaf(d, d, sc);
            d = acc[4 * g + 1] - m4.y; sc = fmaf(d, d, sc);
            d = acc[4 * g + 2] - m4.z; sc = fmaf(d, d, sc);
            d = acc[4 * g + 3] - m4.w; sc = fmaf(d, d, sc);
          }
        }
        sc += __shfl_xor(sc, 32, 64);
        if (h == 0) sc_s[rowhalf * 32 + ln31][cbase + cl_] = sc;
      }
    }
    __syncthreads();
    {
      const int r = t & 63, cq = t >> 6, b = r >> 4;
      float s[16];
#pragma unroll
      for (int cc = 0; cc < 16; ++cc) s[cc] = T_s[b * CC + cc] - sc_s[r][cc];
      float m = s[0];
#pragma unroll
      for (int cc = 1; cc < 16; ++cc) m = fmaxf(m, s[cc]);
      float den = 0.f;
#pragma unroll
      for (int cc = 0; cc < 16; ++cc) { s[cc] = __expf(s[cc] - m); den += s[cc]; }
      const float a = act_s[r] / den;
#pragma unroll
      for (int k = 0; k < 2; ++k) {
        const int cc = 2 * cq + k;
        const float rh = fmaxf(s[cc] * a, 0.01f);
        rh2[cc][r] = rh;
        atomicAdd(&sr_s[b * CC + cc], rh);
      }
    }
    __syncthreads();
  }

#pragma unroll
  for (int pair = 0; pair < 2; ++pair) {
    ABfrag A;
    {
      const int r = pair * 32 + ln31;
      A.h[0] = *reinterpret_cast<const short4v*>(&pbf[r][8 * h]);
      A.h[1] = *reinterpret_cast<const short4v*>(&pbf[r][8 * h + 4]);
    }
    float p1[4][2] = {}, p2[4][2] = {};
#pragma unroll
    for (int cl_ = 0; cl_ < 2; ++cl_) {
      float rq[16];
      if (PASS == 1) {
#pragma unroll
        for (int g = 0; g < 4; ++g) {
          const float4 v = *reinterpret_cast<const float4*>(
              &rh2[cbase + cl_][pair * 32 + 8 * g + 4 * h]);
          rq[4 * g + 0] = v.x; rq[4 * g + 1] = v.y;
          rq[4 * g + 2] = v.z; rq[4 * g + 3] = v.w;
        }
      } else {
#pragma unroll
        for (int g = 0; g < 4; ++g) {
          const float4 v = *reinterpret_cast<const float4*>(
              &act_s[pair * 32 + 8 * g + 4 * h]);
          rq[4 * g + 0] = fmaxf(v.x * 0.0625f, 0.01f);
          rq[4 * g + 1] = fmaxf(v.y * 0.0625f, 0.01f);
          rq[4 * g + 2] = fmaxf(v.z * 0.0625f, 0.01f);
          rq[4 * g + 3] = fmaxf(v.w * 0.0625f, 0.01f);
        }
      }
#pragma unroll
      for (int lh = 0; lh < 2; ++lh) {
        const f32x16 acc = __builtin_amdgcn_mfma_f32_32x32x16_bf16(
            A.v, wf[cl_ * 2 + lh], zero16, 0, 0, 0);
        const int t4 = cl_ * 2 + lh;
#pragma unroll
        for (int j = 0; j < 16; ++j) {
          const float v = acc[j];
          const float rv = rq[j] * v;
          p1[t4][j >> 3] += rv;
          p2[t4][j >> 3] = fmaf(rv, v, p2[t4][j >> 3]);
        }
      }
    }
#pragma unroll
    for (int t4 = 0; t4 < 4; ++t4)
#pragma unroll
      for (int bh = 0; bh < 2; ++bh) {
        float v1 = p1[t4][bh]; v1 += __shfl_xor(v1, 32, 64);
        float v2 = p2[t4][bh]; v2 += __shfl_xor(v2, 32, 64);
        const int b = pair * 2 + bh, c = cbase + (t4 >> 1);
        const int idx = (b * CC + c) * LV + (t4 & 1) * 32 + ln31;
        if (h == 0) { atomicAdd(&S1p[idx], v1); atomicAdd(&S2p[idx], v2); }
      }
  }

  if (PASS == 1) {
    if (t < 64) atomicAdd(&Srp[t], sr_s[t]);
  } else {
    if (t < 64) {
      const int b = t >> 4;
      float s = 0.f;
#pragma unroll
      for (int xy = 0; xy < 16; ++xy) s += fmaxf(act_s[b * 16 + xy] * 0.0625f, 0.01f);
      atomicAdd(&Srp[t], s);
    }
  }
}

__global__ void reduce_slabs(const float* __restrict__ Spart, float* __restrict__ Sred,
                             int nslab, int chunk) {
  const int idx = blockIdx.x * 256 + threadIdx.x;
  if (idx >= SLABTOT) return;
  const int s0 = blockIdx.y * chunk;
  const int s1 = min(s0 + chunk, nslab);
  float a = 0.f;
#pragma unroll 8
  for (int s = s0; s < s1; s++) a += Spart[(size_t)s * SLABTOT + idx];
  atomicAdd(&Sred[idx], a);
}

template <int FINAL>
__global__ void stats_post(const float* __restrict__ Sred,
                           const float* __restrict__ beta_v,
                           const float* __restrict__ beta_a,
                           const float* __restrict__ lam,
                           float* __restrict__ mu_out, float* __restrict__ T_out,
                           float* __restrict__ out) {
  __shared__ float lsum_s[64][8];
  const int t = threadIdx.x;
  const int bc = t >> 3, part = t & 7;
  const float inv = 1.f / Sred[2 * SLAB + bc];
  float lsl = 0.f;
#pragma unroll
  for (int q = 0; q < 8; ++q) {
    const int l = part * 8 + q;
    const int idx = bc * 64 + l;
    const float m = Sred[idx] * inv;
    const float s2 = fmaxf(Sred[SLAB + idx] * inv - m * m, 0.01f);
    lsl += logf(s2);
    if (FINAL) out[(size_t)(bc >> 4) * 1040 + (bc & 15) * 64 + l] = m;
    else mu_out[idx] = m;
  }
  lsum_s[bc][part] = lsl;
  __syncthreads();
  if (t < 64) {
    float lsum = 0.f;
#pragma unroll
    for (int q = 0; q < 8; ++q) lsum += lsum_s[t][q];
    const float sr = Sred[2 * SLAB + t];
    const float z = lam[0] * (beta_a[t & 15] - (64.f * beta_v[0] + lsum) * sr);
    const float ac = 1.f / (1.f + expf(-z));
    if (FINAL) out[(size_t)(t >> 4) * 1040 + 1024 + (t & 15)] = ac;
    else T_out[t] = logf(ac) - 0.5f * (64.f * LOG_2PI_F + lsum);
  }
}

extern "C" void kernel_launch(void* const* d_in, const int* in_sizes, int n_in,
                              void* d_out, int out_size, void* d_ws, size_t ws_size,
                              hipStream_t stream) {
  const float* x = (const float*)d_in[0];
  const float* W = (const float*)d_in[1];
  const float* beta_v = (const float*)d_in[2];
  const float* beta_a = (const float*)d_in[3];
  const float* lam = (const float*)d_in[4];
  float* out = (float*)d_out;

  // cache-path layout: Spart(512 slabs) | Sred | WbfC | poseC | actC | Spart2(16)
  const size_t need_cache =
      ((size_t)NB2 * SLABTOT + SLABTOT) * sizeof(float) + WBF_ELEMS * 2 +
      POSE_ELEMS * 2 + ACT_ELEMS * sizeof(float) +
      (size_t)16 * SLABTOT * sizeof(float);

  float* Spart = (float*)d_ws;

  if (ws_size >= need_cache) {
    float* Sred = Spart + (size_t)NB2 * SLABTOT;
    unsigned short* WbfC = (unsigned short*)(Sred + SLABTOT);
    unsigned short* poseC = WbfC + WBF_ELEMS;
    float* actC = (float*)(poseC + POSE_ELEMS);
    float* Spart2 = actC + ACT_ELEMS;

    const dim3 agrid((SLABTOT + 255) / 256, 16);  // 512 slabs / 32
    const dim3 bgrid((SLABTOT + 255) / 256);
    // ---- pass 0 ----
    em_sweep2<0><<<dim3(NB2), dim3(512), 0, stream>>>(
        x, W, nullptr, beta_v, beta_a, lam, Spart, WbfC, poseC, actC);
    reduce_stageA<<<agrid, dim3(256), 0, stream>>>(Spart, Spart2);
    reduce_stageB<<<bgrid, dim3(256), 0, stream>>>(Spart2, Sred, 16);
    // ---- pass 1 (mu/T computed in-block from Sred) ----
    em_sweep2<1><<<dim3(NB2), dim3(512), 0, stream>>>(
        x, W, Sred, beta_v, beta_a, lam, Spart, WbfC, poseC, actC);
    reduce_stageA<<<agrid, dim3(256), 0, stream>>>(Spart, Spart2);
    reduce_stageB<<<bgrid, dim3(256), 0, stream>>>(Spart2, Sred, 16);
    stats_final<<<dim3(1), dim3(512), 0, stream>>>(Sred, beta_v, beta_a, lam, out);
    return;
  }

  // ---- fallback: legacy memset + atomic reduce (32 slabs, 1024 blocks) ----
  const int nslab = NSLAB_SM;
  float* Sred = Spart + (size_t)nslab * SLABTOT;
  float* muW = Sred + SLABTOT;
  float* Tw = muW + SLAB;
  const int chunk = 32;
  const dim3 rgrid((SLABTOT + 255) / 256, (nslab + chunk - 1) / chunk);

  hipMemsetAsync(Spart, 0, (size_t)nslab * SLABTOT * sizeof(float), stream);
  hipMemsetAsync(Sred, 0, SLABTOT * sizeof(float), stream);
  em_sweep_legacy<0><<<dim3(BC), dim3(512), 0, stream>>>(x, W, nullptr, nullptr, Spart, nslab);
  reduce_slabs<<<rgrid, dim3(256), 0, stream>>>(Spart, Sred, nslab, chunk);
  stats_post<0><<<dim3(1), dim3(512), 0, stream>>>(Sred, beta_v, beta_a, lam, muW, Tw, nullptr);

  hipMemsetAsync(Spart, 0, (size_t)nslab * SLABTOT * sizeof(float), stream);
  em_sweep_legacy<1><<<dim3(BC), dim3(512), 0, stream>>>(x, W, muW, Tw, Spart, nslab);
  hipMemsetAsync(Sred, 0, SLABTOT * sizeof(float), stream);
  reduce_slabs<<<rgrid, dim3(256), 0, stream>>>(Spart, Sred, nslab, chunk);
  stats_post<1><<<dim3(1), dim3(512), 0, stream>>>(Sred, beta_v, beta_a, lam, nullptr, nullptr, out);
}

// Round 20
// 78.468 us; speedup vs baseline: 1.0674x; 1.0049x over previous
//
#include <hip/hip_runtime.h>

#define LOG_2PI_F 1.8378770664093453f

constexpr int BC = 1024, CC = 16, PV = 16, LV = 64, BB = 4;
constexpr int CH = (PV + 1) * BC;
constexpr int SLAB = BB * CC * LV;           // 4096
constexpr int SLABTOT = 2 * SLAB + BB * CC;  // 8256
constexpr int NB2 = 512;                     // 2-cap grid
constexpr int NSLAB_SM = 32;
constexpr size_t WBF_ELEMS = (size_t)CC * BC * LV * PV;   // 16.7M shorts
constexpr size_t POSE_ELEMS = (size_t)BC * 64 * 16;       // shorts
constexpr size_t ACT_ELEMS = (size_t)BC * 64;             // floats

typedef __attribute__((ext_vector_type(4))) short short4v;
typedef __attribute__((ext_vector_type(8))) short short8v;
typedef __attribute__((ext_vector_type(16))) float f32x16;

union ABfrag { short8v v; short4v h[2]; unsigned short u[8]; };

__device__ __forceinline__ unsigned short f2bf(float f) {
  unsigned u = __float_as_uint(f);
  u += 0x7fffu + ((u >> 16) & 1u);  // RNE
  return (unsigned short)(u >> 16);
}

// HW packed conversion: v_cvt_pk_bf16_f32 (RNE), 1 inst per 2 floats.
// (Baseline f2bf bit-math is ~5 inst/value and NOT compiler-fusable.)
__device__ __forceinline__ short8v cvt8(const float4 a, const float4 b) {
  union { short8v v; unsigned int q[4]; } f;
  asm("v_cvt_pk_bf16_f32 %0, %1, %2" : "=v"(f.q[0]) : "v"(a.x), "v"(a.y));
  asm("v_cvt_pk_bf16_f32 %0, %1, %2" : "=v"(f.q[1]) : "v"(a.z), "v"(a.w));
  asm("v_cvt_pk_bf16_f32 %0, %1, %2" : "=v"(f.q[2]) : "v"(b.x), "v"(b.y));
  asm("v_cvt_pk_bf16_f32 %0, %1, %2" : "=v"(f.q[3]) : "v"(b.z), "v"(b.w));
  return f.v;
}

// ===== 2-caps-per-block sweep (512 thr / 8 waves / 2c per wave, grid 512) =====
// PASS1 (round 19): barrier-batched phases -- [A0,A1, bar, softmax(both),
// bar, B0,B1]; wf reloaded per phase from bf16 cache (dead between phases ->
// no spill; rounds 8/9/13 lesson). Cross-cap S1/S2 accumulate in LDS Sacc.
// MFMA v_mfma_f32_32x32x16_bf16: A m=lane&31,k=8h+j ;
// C/D col=lane&31,row=(reg&3)+8*(reg>>2)+4*h [m74/m101].
// Phase A: SWAPPED mfma(W,pose) -> l-sum in-register + 1 shfl_xor(32).
// Phase B: mfma(pose,W), r-sum in-register, h==0 lanes write/add Sacc.
// PASS1 computes mu_s/T_s in-block from Sred (33KB broadcast, L2-resident).
template <int PASS>
__global__ __launch_bounds__(512, 4) void em_sweep2(
    const float* __restrict__ x, const float* __restrict__ W,
    const float* __restrict__ SredIn, const float* __restrict__ beta_v,
    const float* __restrict__ beta_a, const float* __restrict__ lam,
    float* __restrict__ Spart,
    unsigned short* __restrict__ WbfC, unsigned short* __restrict__ poseC,
    float* __restrict__ actC) {
  const int bid = blockIdx.x, t = threadIdx.x;
  const int w = t >> 6, lane = t & 63;
  const int ln31 = lane & 31, h = lane >> 5;
  const int cbase = 2 * w;

  float* slab = Spart + (size_t)bid * SLABTOT;

  __shared__ __align__(16) unsigned short pbf[2][64][20];  // pitch 40B
  __shared__ float act_s[2][64];
  __shared__ float T_s[64];
  __shared__ float sr_s[64];
  __shared__ float sc_s[2][64][17];
  __shared__ __align__(16) float rh2[2][16][64];
  __shared__ __align__(16) float mu_s[64][64];
  __shared__ float lsum_s[64][8];
  __shared__ float Sacc[SLABTOT];  // cross-cap accumulator (LDS, not regs!)

  const f32x16 zero16 = {};

  if (PASS == 1) {
    // ---- prologue: stage pose/act, mu/T from Sred ----
    if (t < 256) {  // pose from bf16 cache, clean 16B chunks
      const int cap = t >> 7, tt = t & 127;
      const int r = tt >> 1, half = tt & 1;
      const int i = bid + cap * NB2;
      const int4 v = *reinterpret_cast<const int4*>(
          poseC + ((size_t)i * 64 + r) * 16 + 8 * half);
      union { int4 q; short4v s[2]; } u;
      u.q = v;
      *reinterpret_cast<short4v*>(&pbf[cap][r][8 * half]) = u.s[0];
      *reinterpret_cast<short4v*>(&pbf[cap][r][8 * half + 4]) = u.s[1];
    }
    if (t < 128) {
      const int cap = t >> 6, r = t & 63;
      act_s[cap][r] = actC[(size_t)(bid + cap * NB2) * 64 + r];
    }
    if (t < 64) sr_s[t] = 0.f;
    {
      const int bc = t >> 3, part = t & 7;
      const float inv = 1.f / SredIn[2 * SLAB + bc];
      float lsl = 0.f;
#pragma unroll
      for (int q = 0; q < 8; ++q) {
        const int idx = bc * 64 + part * 8 + q;
        const float m = SredIn[idx] * inv;
        const float s2 = fmaxf(SredIn[SLAB + idx] * inv - m * m, 0.01f);
        lsl += logf(s2);
        mu_s[bc][part * 8 + q] = m;
      }
      lsum_s[bc][part] = lsl;
    }
    __syncthreads();
    if (t < 64) {
      float lsum = 0.f;
#pragma unroll
      for (int q = 0; q < 8; ++q) lsum += lsum_s[t][q];
      const float sr = SredIn[2 * SLAB + t];
      const float z = lam[0] * (beta_a[t & 15] - (64.f * beta_v[0] + lsum) * sr);
      const float ac = 1.f / (1.f + expf(-z));
      T_s[t] = logf(ac) - 0.5f * (64.f * LOG_2PI_F + lsum);
    }
    __syncthreads();

    // ---- phase A for BOTH caps (back-to-back, no barrier between) ----
#pragma unroll
    for (int cap = 0; cap < 2; ++cap) {
      const int i = bid + cap * NB2;
      short8v wf[4];
#pragma unroll
      for (int k = 0; k < 4; ++k) {
        const int cl_ = k >> 1, lh = k & 1;
        const size_t off = ((size_t)(cbase + cl_) * BC + i) * 1024 +
                           (lh * 32 + ln31) * 16 + 8 * h;
        wf[k] = *reinterpret_cast<const short8v*>(WbfC + off);
      }
#pragma unroll
      for (int rowhalf = 0; rowhalf < 2; ++rowhalf) {
        ABfrag A;
        {
          const int r = rowhalf * 32 + ln31;
          A.h[0] = *reinterpret_cast<const short4v*>(&pbf[cap][r][8 * h]);
          A.h[1] = *reinterpret_cast<const short4v*>(&pbf[cap][r][8 * h + 4]);
        }
        const int b = (rowhalf * 32 + ln31) >> 4;
#pragma unroll
        for (int cl_ = 0; cl_ < 2; ++cl_) {
          float sc = 0.f;
#pragma unroll
          for (int lh = 0; lh < 2; ++lh) {
            const f32x16 acc = __builtin_amdgcn_mfma_f32_32x32x16_bf16(
                wf[cl_ * 2 + lh], A.v, zero16, 0, 0, 0);
            const float* mrow = &mu_s[b * CC + cbase + cl_][lh * 32 + 4 * h];
#pragma unroll
            for (int g = 0; g < 4; ++g) {
              const float4 m4 = *reinterpret_cast<const float4*>(mrow + 8 * g);
              float d;
              d = acc[4 * g + 0] - m4.x; sc = fmaf(d, d, sc);
              d = acc[4 * g + 1] - m4.y; sc = fmaf(d, d, sc);
              d = acc[4 * g + 2] - m4.z; sc = fmaf(d, d, sc);
              d = acc[4 * g + 3] - m4.w; sc = fmaf(d, d, sc);
            }
          }
          sc += __shfl_xor(sc, 32, 64);
          if (h == 0) sc_s[cap][rowhalf * 32 + ln31][cbase + cl_] = sc;
        }
      }
    }
    __syncthreads();

    // ---- softmax over c, both caps ----
#pragma unroll
    for (int cap = 0; cap < 2; ++cap) {
      const int r = t & 63, cq = t >> 6, b = r >> 4;
      float s[16];
#pragma unroll
      for (int cc = 0; cc < 16; ++cc) s[cc] = T_s[b * CC + cc] - sc_s[cap][r][cc];
      float m = s[0];
#pragma unroll
      for (int cc = 1; cc < 16; ++cc) m = fmaxf(m, s[cc]);
      float den = 0.f;
#pragma unroll
      for (int cc = 0; cc < 16; ++cc) { s[cc] = __expf(s[cc] - m); den += s[cc]; }
      const float a = act_s[cap][r] / den;
#pragma unroll
      for (int k = 0; k < 2; ++k) {
        const int cc = 2 * cq + k;
        const float rh = fmaxf(s[cc] * a, 0.01f);
        rh2[cap][cc][r] = rh;
        atomicAdd(&sr_s[b * CC + cc], rh);
      }
    }
    __syncthreads();

    // ---- phase B for BOTH caps (back-to-back) ----
#pragma unroll
    for (int cap = 0; cap < 2; ++cap) {
      const int i = bid + cap * NB2;
      short8v wf[4];
#pragma unroll
      for (int k = 0; k < 4; ++k) {
        const int cl_ = k >> 1, lh = k & 1;
        const size_t off = ((size_t)(cbase + cl_) * BC + i) * 1024 +
                           (lh * 32 + ln31) * 16 + 8 * h;
        wf[k] = *reinterpret_cast<const short8v*>(WbfC + off);
      }
#pragma unroll
      for (int pair = 0; pair < 2; ++pair) {
        ABfrag A;
        {
          const int r = pair * 32 + ln31;
          A.h[0] = *reinterpret_cast<const short4v*>(&pbf[cap][r][8 * h]);
          A.h[1] = *reinterpret_cast<const short4v*>(&pbf[cap][r][8 * h + 4]);
        }
        float p1[4][2] = {}, p2[4][2] = {};
#pragma unroll
        for (int cl_ = 0; cl_ < 2; ++cl_) {
          float rq[16];
#pragma unroll
          for (int g = 0; g < 4; ++g) {
            const float4 v = *reinterpret_cast<const float4*>(
                &rh2[cap][cbase + cl_][pair * 32 + 8 * g + 4 * h]);
            rq[4 * g + 0] = v.x; rq[4 * g + 1] = v.y;
            rq[4 * g + 2] = v.z; rq[4 * g + 3] = v.w;
          }
#pragma unroll
          for (int lh = 0; lh < 2; ++lh) {
            const f32x16 acc = __builtin_amdgcn_mfma_f32_32x32x16_bf16(
                A.v, wf[cl_ * 2 + lh], zero16, 0, 0, 0);
            const int t4 = cl_ * 2 + lh;
#pragma unroll
            for (int j = 0; j < 16; ++j) {
              const float v = acc[j];
              const float rv = rq[j] * v;
              p1[t4][j >> 3] += rv;
              p2[t4][j >> 3] = fmaf(rv, v, p2[t4][j >> 3]);
            }
          }
        }
#pragma unroll
        for (int t4 = 0; t4 < 4; ++t4)
#pragma unroll
          for (int bh = 0; bh < 2; ++bh) {
            float v1 = p1[t4][bh]; v1 += __shfl_xor(v1, 32, 64);
            float v2 = p2[t4][bh]; v2 += __shfl_xor(v2, 32, 64);
            const int b = pair * 2 + bh, c = cbase + (t4 >> 1);
            const int idx = (b * CC + c) * LV + (t4 & 1) * 32 + ln31;
            if (h == 0) {
              if (cap == 0) { Sacc[idx] = v1; Sacc[SLAB + idx] = v2; }
              else          { Sacc[idx] += v1; Sacc[SLAB + idx] += v2; }
            }
          }
      }
    }
    if (t < 64) Sacc[2 * SLAB + t] = sr_s[t];
  } else {
    // ================= PASS 0 (round-15 structure; HW cvt_pk) =================
    {
      const int cap = t >> 8, tt = t & 255;
      const int b = tt >> 6, p = (tt >> 2) & 15, q = tt & 3;
      const int i = bid + cap * NB2;
      const float4 v = *reinterpret_cast<const float4*>(
          x + ((size_t)(b * CH + p * BC + i)) * 16 + 4 * q);
      pbf[cap][b * 16 + 4 * q + 0][p] = f2bf(v.x);
      pbf[cap][b * 16 + 4 * q + 1][p] = f2bf(v.y);
      pbf[cap][b * 16 + 4 * q + 2][p] = f2bf(v.z);
      pbf[cap][b * 16 + 4 * q + 3][p] = f2bf(v.w);
    }
    if (t < 128) {
      const int cap = t >> 6, r = t & 63;
      const int b = r >> 4, xy = r & 15;
      const float a = x[((size_t)(b * CH + PV * BC + bid + cap * NB2)) * 16 + xy];
      act_s[cap][r] = a;
      actC[(size_t)(bid + cap * NB2) * 64 + r] = a;
    }
    __syncthreads();
    // persist pose-bf16 (reads LDS after barrier)
    if (t < 256) {
      const int cap = t >> 7, tt = t & 127;
      const int r = tt >> 1, half = tt & 1;
      const int i = bid + cap * NB2;
      union { int4 q; short4v s[2]; } u;
      u.s[0] = *reinterpret_cast<const short4v*>(&pbf[cap][r][8 * half]);
      u.s[1] = *reinterpret_cast<const short4v*>(&pbf[cap][r][8 * half + 4]);
      *reinterpret_cast<int4*>(poseC + ((size_t)i * 64 + r) * 16 + 8 * half) = u.q;
    }

#pragma unroll
    for (int cap = 0; cap < 2; ++cap) {
      const int i = bid + cap * NB2;
      short8v wf[4];
#pragma unroll
      for (int k = 0; k < 4; ++k) {
        const int cl_ = k >> 1, lh = k & 1;
        const float* src = W + ((size_t)(cbase + cl_) * BC + i) * 1024 +
                           (lh * 32 + ln31) * 16 + 8 * h;
        const float4 v0 = *reinterpret_cast<const float4*>(src);
        const float4 v1 = *reinterpret_cast<const float4*>(src + 4);
        wf[k] = cvt8(v0, v1);  // convert immediately (spill-proof), HW cvt_pk
      }
#pragma unroll
      for (int k = 0; k < 4; ++k) asm volatile("" : "+v"(wf[k]));  // pin live
#pragma unroll
      for (int k = 0; k < 4; ++k) {
        const int cl_ = k >> 1, lh = k & 1;
        const size_t off = ((size_t)(cbase + cl_) * BC + i) * 1024 +
                           (lh * 32 + ln31) * 16 + 8 * h;
        *reinterpret_cast<short8v*>(WbfC + off) = wf[k];
      }

#pragma unroll
      for (int pair = 0; pair < 2; ++pair) {
        ABfrag A;
        {
          const int r = pair * 32 + ln31;
          A.h[0] = *reinterpret_cast<const short4v*>(&pbf[cap][r][8 * h]);
          A.h[1] = *reinterpret_cast<const short4v*>(&pbf[cap][r][8 * h + 4]);
        }
        float p1[4][2] = {}, p2[4][2] = {};
#pragma unroll
        for (int cl_ = 0; cl_ < 2; ++cl_) {
          float rq[16];
#pragma unroll
          for (int g = 0; g < 4; ++g) {
            const float4 v = *reinterpret_cast<const float4*>(
                &act_s[cap][pair * 32 + 8 * g + 4 * h]);
            rq[4 * g + 0] = fmaxf(v.x * 0.0625f, 0.01f);
            rq[4 * g + 1] = fmaxf(v.y * 0.0625f, 0.01f);
            rq[4 * g + 2] = fmaxf(v.z * 0.0625f, 0.01f);
            rq[4 * g + 3] = fmaxf(v.w * 0.0625f, 0.01f);
          }
#pragma unroll
          for (int lh = 0; lh < 2; ++lh) {
            const f32x16 acc = __builtin_amdgcn_mfma_f32_32x32x16_bf16(
                A.v, wf[cl_ * 2 + lh], zero16, 0, 0, 0);
            const int t4 = cl_ * 2 + lh;
#pragma unroll
            for (int j = 0; j < 16; ++j) {
              const float v = acc[j];
              const float rv = rq[j] * v;
              p1[t4][j >> 3] += rv;
              p2[t4][j >> 3] = fmaf(rv, v, p2[t4][j >> 3]);
            }
          }
        }
#pragma unroll
        for (int t4 = 0; t4 < 4; ++t4)
#pragma unroll
          for (int bh = 0; bh < 2; ++bh) {
            float v1 = p1[t4][bh]; v1 += __shfl_xor(v1, 32, 64);
            float v2 = p2[t4][bh]; v2 += __shfl_xor(v2, 32, 64);
            const int b = pair * 2 + bh, c = cbase + (t4 >> 1);
            const int idx = (b * CC + c) * LV + (t4 & 1) * 32 + ln31;
            if (h == 0) {
              if (cap == 0) { Sacc[idx] = v1; Sacc[SLAB + idx] = v2; }
              else          { Sacc[idx] += v1; Sacc[SLAB + idx] += v2; }
            }
          }
      }
    }
    if (t < 64) {
      const int b = t >> 4;
      float s = 0.f;
#pragma unroll
      for (int cp = 0; cp < 2; ++cp)
#pragma unroll
        for (int xy = 0; xy < 16; ++xy)
          s += fmaxf(act_s[cp][b * 16 + xy] * 0.0625f, 0.01f);
      Sacc[2 * SLAB + t] = s;
    }
  }

  __syncthreads();
  for (int idx = t; idx < SLABTOT; idx += 512) slab[idx] = Sacc[idx];
}

// ---- two-stage tree reduce, plain stores ----
__global__ void reduce_stageA(const float* __restrict__ Spart,
                              float* __restrict__ Spart2) {
  const int idx = blockIdx.x * 256 + threadIdx.x;
  if (idx >= SLABTOT) return;
  const float* base = Spart + (size_t)(blockIdx.y * 32) * SLABTOT + idx;
  float a = 0.f;
#pragma unroll 8
  for (int s = 0; s < 32; ++s) a += base[(size_t)s * SLABTOT];
  Spart2[(size_t)blockIdx.y * SLABTOT + idx] = a;
}

__global__ void reduce_stageB(const float* __restrict__ Spart2,
                              float* __restrict__ Sred, int nchunk) {
  const int idx = blockIdx.x * 256 + threadIdx.x;
  if (idx >= SLABTOT) return;
  float a = 0.f;
  for (int s = 0; s < nchunk; ++s) a += Spart2[(size_t)s * SLABTOT + idx];
  Sred[idx] = a;
}

// ---- final stats (512 threads) ----
__global__ void stats_final(const float* __restrict__ Sred,
                            const float* __restrict__ beta_v,
                            const float* __restrict__ beta_a,
                            const float* __restrict__ lam,
                            float* __restrict__ out) {
  __shared__ float lsum_s[64][8];
  const int t = threadIdx.x;
  const int bc = t >> 3, part = t & 7;
  const float inv = 1.f / Sred[2 * SLAB + bc];
  float lsl = 0.f;
#pragma unroll
  for (int q = 0; q < 8; ++q) {
    const int l = part * 8 + q;
    const int idx = bc * 64 + l;
    const float m = Sred[idx] * inv;
    const float s2 = fmaxf(Sred[SLAB + idx] * inv - m * m, 0.01f);
    lsl += logf(s2);
    out[(size_t)(bc >> 4) * 1040 + (bc & 15) * 64 + l] = m;
  }
  lsum_s[bc][part] = lsl;
  __syncthreads();
  if (t < 64) {
    float lsum = 0.f;
#pragma unroll
    for (int q = 0; q < 8; ++q) lsum += lsum_s[t][q];
    const float sr = Sred[2 * SLAB + t];
    const float z = lam[0] * (beta_a[t & 15] - (64.f * beta_v[0] + lsum) * sr);
    out[(size_t)(t >> 4) * 1040 + 1024 + (t & 15)] = 1.f / (1.f + expf(-z));
  }
}

// ===== legacy single-cap fallback (round-12 proven; small-ws only) =====
template <int PASS>
__global__ __launch_bounds__(512, 4) void em_sweep_legacy(
    const float* __restrict__ x, const float* __restrict__ W,
    const float* __restrict__ mu, const float* __restrict__ T,
    float* __restrict__ Spart, int nslab) {
  const int i = blockIdx.x, t = threadIdx.x;
  const int w = t >> 6, lane = t & 63;
  const int ln31 = lane & 31, h = lane >> 5;
  const int cbase = 2 * w;

  float* S1p = Spart + (size_t)(i % nslab) * SLABTOT;
  float* S2p = S1p + SLAB;
  float* Srp = S1p + 2 * SLAB;

  __shared__ __align__(16) unsigned short pbf[64][20];
  __shared__ float act_s[64];
  __shared__ float T_s[64];
  __shared__ float sr_s[64];
  __shared__ float sc_s[64][17];
  __shared__ float rh2[16][64];
  __shared__ __align__(16) float mu_s[64][64];

  short8v wf[4];
#pragma unroll
  for (int k = 0; k < 4; ++k) {
    const int cl_ = k >> 1, lh = k & 1;
    const float* src = W + ((size_t)(cbase + cl_) * BC + i) * 1024 +
                       (lh * 32 + ln31) * 16 + 8 * h;
    const float4 v0 = *reinterpret_cast<const float4*>(src);
    const float4 v1 = *reinterpret_cast<const float4*>(src + 4);
    wf[k] = cvt8(v0, v1);
  }
#pragma unroll
  for (int k = 0; k < 4; ++k) asm volatile("" : "+v"(wf[k]));

  if (t < 256) {
    const int b = t >> 6, p = (t >> 2) & 15, q = t & 3;
    const float4 v = *reinterpret_cast<const float4*>(
        x + ((size_t)(b * CH + p * BC + i)) * 16 + 4 * q);
    pbf[b * 16 + 4 * q + 0][p] = f2bf(v.x);
    pbf[b * 16 + 4 * q + 1][p] = f2bf(v.y);
    pbf[b * 16 + 4 * q + 2][p] = f2bf(v.z);
    pbf[b * 16 + 4 * q + 3][p] = f2bf(v.w);
  }
  if (t < 64) {
    const int b = t >> 4, xy = t & 15;
    act_s[t] = x[((size_t)(b * CH + PV * BC + i)) * 16 + xy];
    if (PASS == 1) { T_s[t] = T[t]; sr_s[t] = 0.f; }
  }
  if (PASS == 1) {
    const float4* msrc = reinterpret_cast<const float4*>(mu);
    float4* mdst = reinterpret_cast<float4*>(&mu_s[0][0]);
    mdst[t] = msrc[t];
    mdst[t + 512] = msrc[t + 512];
  }
  __syncthreads();

  const f32x16 zero16 = {};

  if (PASS == 1) {
#pragma unroll
    for (int rowhalf = 0; rowhalf < 2; ++rowhalf) {
      ABfrag A;
      {
        const int r = rowhalf * 32 + ln31;
        A.h[0] = *reinterpret_cast<const short4v*>(&pbf[r][8 * h]);
        A.h[1] = *reinterpret_cast<const short4v*>(&pbf[r][8 * h + 4]);
      }
      const int b = (rowhalf * 32 + ln31) >> 4;
#pragma unroll
      for (int cl_ = 0; cl_ < 2; ++cl_) {
        float sc = 0.f;
#pragma unroll
        for (int lh = 0; lh < 2; ++lh) {
          const f32x16 acc = __builtin_amdgcn_mfma_f32_32x32x16_bf16(
              wf[cl_ * 2 + lh], A.v, zero16, 0, 0, 0);
          const float* mrow = &mu_s[b * CC + cbase + cl_][lh * 32 + 4 * h];
#pragma unroll
          for (int g = 0; g < 4; ++g) {
            const float4 m4 = *reinterpret_cast<const float4*>(mrow + 8 * g);
            float d;
            d = acc[4 * g + 0] - m4.x; sc = fmaf(d, d, sc);
            d = acc[4 * g + 1] - m4.y; sc = fmaf(d, d, sc);
            d = acc[4 * g + 2] - m4.z; sc = fmaf(d, d, sc);
            d = acc[4 * g + 3] - m4.w; sc = fmaf(d, d, sc);
          }
        }
        sc += __shfl_xor(sc, 32, 64);
        if (h == 0) sc_s[rowhalf * 32 + ln31][cbase + cl_] = sc;
      }
    }
    __syncthreads();
    {
      const int r = t & 63, cq = t >> 6, b = r >> 4;
      float s[16];
#pragma unroll
      for (int cc = 0; cc < 16; ++cc) s[cc] = T_s[b * CC + cc] - sc_s[r][cc];
      float m = s[0];
#pragma unroll
      for (int cc = 1; cc < 16; ++cc) m = fmaxf(m, s[cc]);
      float den = 0.f;
#pragma unroll
      for (int cc = 0; cc < 16; ++cc) { s[cc] = __expf(s[cc] - m); den += s[cc]; }
      const float a = act_s[r] / den;
#pragma unroll
      for (int k = 0; k < 2; ++k) {
        const int cc = 2 * cq + k;
        const float rh = fmaxf(s[cc] * a, 0.01f);
        rh2[cc][r] = rh;
        atomicAdd(&sr_s[b * CC + cc], rh);
      }
    }
    __syncthreads();
  }

#pragma unroll
  for (int pair = 0; pair < 2; ++pair) {
    ABfrag A;
    {
      const int r = pair * 32 + ln31;
      A.h[0] = *reinterpret_cast<const short4v*>(&pbf[r][8 * h]);
      A.h[1] = *reinterpret_cast<const short4v*>(&pbf[r][8 * h + 4]);
    }
    float p1[4][2] = {}, p2[4][2] = {};
#pragma unroll
    for (int cl_ = 0; cl_ < 2; ++cl_) {
      float rq[16];
      if (PASS == 1) {
#pragma unroll
        for (int g = 0; g < 4; ++g) {
          const float4 v = *reinterpret_cast<const float4*>(
              &rh2[cbase + cl_][pair * 32 + 8 * g + 4 * h]);
          rq[4 * g + 0] = v.x; rq[4 * g + 1] = v.y;
          rq[4 * g + 2] = v.z; rq[4 * g + 3] = v.w;
        }
      } else {
#pragma unroll
        for (int g = 0; g < 4; ++g) {
          const float4 v = *reinterpret_cast<const float4*>(
              &act_s[pair * 32 + 8 * g + 4 * h]);
          rq[4 * g + 0] = fmaxf(v.x * 0.0625f, 0.01f);
          rq[4 * g + 1] = fmaxf(v.y * 0.0625f, 0.01f);
          rq[4 * g + 2] = fmaxf(v.z * 0.0625f, 0.01f);
          rq[4 * g + 3] = fmaxf(v.w * 0.0625f, 0.01f);
        }
      }
#pragma unroll
      for (int lh = 0; lh < 2; ++lh) {
        const f32x16 acc = __builtin_amdgcn_mfma_f32_32x32x16_bf16(
            A.v, wf[cl_ * 2 + lh], zero16, 0, 0, 0);
        const int t4 = cl_ * 2 + lh;
#pragma unroll
        for (int j = 0; j < 16; ++j) {
          const float v = acc[j];
          const float rv = rq[j] * v;
          p1[t4][j >> 3] += rv;
          p2[t4][j >> 3] = fmaf(rv, v, p2[t4][j >> 3]);
        }
      }
    }
#pragma unroll
    for (int t4 = 0; t4 < 4; ++t4)
#pragma unroll
      for (int bh = 0; bh < 2; ++bh) {
        float v1 = p1[t4][bh]; v1 += __shfl_xor(v1, 32, 64);
        float v2 = p2[t4][bh]; v2 += __shfl_xor(v2, 32, 64);
        const int b = pair * 2 + bh, c = cbase + (t4 >> 1);
        const int idx = (b * CC + c) * LV + (t4 & 1) * 32 + ln31;
        if (h == 0) { atomicAdd(&S1p[idx], v1); atomicAdd(&S2p[idx], v2); }
      }
  }

  if (PASS == 1) {
    if (t < 64) atomicAdd(&Srp[t], sr_s[t]);
  } else {
    if (t < 64) {
      const int b = t >> 4;
      float s = 0.f;
#pragma unroll
      for (int xy = 0; xy < 16; ++xy) s += fmaxf(act_s[b * 16 + xy] * 0.0625f, 0.01f);
      atomicAdd(&Srp[t], s);
    }
  }
}

__global__ void reduce_slabs(const float* __restrict__ Spart, float* __restrict__ Sred,
                             int nslab, int chunk) {
  const int idx = blockIdx.x * 256 + threadIdx.x;
  if (idx >= SLABTOT) return;
  const int s0 = blockIdx.y * chunk;
  const int s1 = min(s0 + chunk, nslab);
  float a = 0.f;
#pragma unroll 8
  for (int s = s0; s < s1; s++) a += Spart[(size_t)s * SLABTOT + idx];
  atomicAdd(&Sred[idx], a);
}

template <int FINAL>
__global__ void stats_post(const float* __restrict__ Sred,
                           const float* __restrict__ beta_v,
                           const float* __restrict__ beta_a,
                           const float* __restrict__ lam,
                           float* __restrict__ mu_out, float* __restrict__ T_out,
                           float* __restrict__ out) {
  __shared__ float lsum_s[64][8];
  const int t = threadIdx.x;
  const int bc = t >> 3, part = t & 7;
  const float inv = 1.f / Sred[2 * SLAB + bc];
  float lsl = 0.f;
#pragma unroll
  for (int q = 0; q < 8; ++q) {
    const int l = part * 8 + q;
    const int idx = bc * 64 + l;
    const float m = Sred[idx] * inv;
    const float s2 = fmaxf(Sred[SLAB + idx] * inv - m * m, 0.01f);
    lsl += logf(s2);
    if (FINAL) out[(size_t)(bc >> 4) * 1040 + (bc & 15) * 64 + l] = m;
    else mu_out[idx] = m;
  }
  lsum_s[bc][part] = lsl;
  __syncthreads();
  if (t < 64) {
    float lsum = 0.f;
#pragma unroll
    for (int q = 0; q < 8; ++q) lsum += lsum_s[t][q];
    const float sr = Sred[2 * SLAB + t];
    const float z = lam[0] * (beta_a[t & 15] - (64.f * beta_v[0] + lsum) * sr);
    const float ac = 1.f / (1.f + expf(-z));
    if (FINAL) out[(size_t)(t >> 4) * 1040 + 1024 + (t & 15)] = ac;
    else T_out[t] = logf(ac) - 0.5f * (64.f * LOG_2PI_F + lsum);
  }
}

extern "C" void kernel_launch(void* const* d_in, const int* in_sizes, int n_in,
                              void* d_out, int out_size, void* d_ws, size_t ws_size,
                              hipStream_t stream) {
  const float* x = (const float*)d_in[0];
  const float* W = (const float*)d_in[1];
  const float* beta_v = (const float*)d_in[2];
  const float* beta_a = (const float*)d_in[3];
  const float* lam = (const float*)d_in[4];
  float* out = (float*)d_out;

  // cache-path layout: Spart(512 slabs) | Sred | WbfC | poseC | actC | Spart2(16)
  const size_t need_cache =
      ((size_t)NB2 * SLABTOT + SLABTOT) * sizeof(float) + WBF_ELEMS * 2 +
      POSE_ELEMS * 2 + ACT_ELEMS * sizeof(float) +
      (size_t)16 * SLABTOT * sizeof(float);

  float* Spart = (float*)d_ws;

  if (ws_size >= need_cache) {
    float* Sred = Spart + (size_t)NB2 * SLABTOT;
    unsigned short* WbfC = (unsigned short*)(Sred + SLABTOT);
    unsigned short* poseC = WbfC + WBF_ELEMS;
    float* actC = (float*)(poseC + POSE_ELEMS);
    float* Spart2 = actC + ACT_ELEMS;

    const dim3 agrid((SLABTOT + 255) / 256, 16);  // 512 slabs / 32
    const dim3 bgrid((SLABTOT + 255) / 256);
    // ---- pass 0 ----
    em_sweep2<0><<<dim3(NB2), dim3(512), 0, stream>>>(
        x, W, nullptr, beta_v, beta_a, lam, Spart, WbfC, poseC, actC);
    reduce_stageA<<<agrid, dim3(256), 0, stream>>>(Spart, Spart2);
    reduce_stageB<<<bgrid, dim3(256), 0, stream>>>(Spart2, Sred, 16);
    // ---- pass 1 (mu/T computed in-block from Sred) ----
    em_sweep2<1><<<dim3(NB2), dim3(512), 0, stream>>>(
        x, W, Sred, beta_v, beta_a, lam, Spart, WbfC, poseC, actC);
    reduce_stageA<<<agrid, dim3(256), 0, stream>>>(Spart, Spart2);
    reduce_stageB<<<bgrid, dim3(256), 0, stream>>>(Spart2, Sred, 16);
    stats_final<<<dim3(1), dim3(512), 0, stream>>>(Sred, beta_v, beta_a, lam, out);
    return;
  }

  // ---- fallback: legacy memset + atomic reduce (32 slabs, 1024 blocks) ----
  const int nslab = NSLAB_SM;
  float* Sred = Spart + (size_t)nslab * SLABTOT;
  float* muW = Sred + SLABTOT;
  float* Tw = muW + SLAB;
  const int chunk = 32;
  const dim3 rgrid((SLABTOT + 255) / 256, (nslab + chunk - 1) / chunk);

  hipMemsetAsync(Spart, 0, (size_t)nslab * SLABTOT * sizeof(float), stream);
  hipMemsetAsync(Sred, 0, SLABTOT * sizeof(float), stream);
  em_sweep_legacy<0><<<dim3(BC), dim3(512), 0, stream>>>(x, W, nullptr, nullptr, Spart, nslab);
  reduce_slabs<<<rgrid, dim3(256), 0, stream>>>(Spart, Sred, nslab, chunk);
  stats_post<0><<<dim3(1), dim3(512), 0, stream>>>(Sred, beta_v, beta_a, lam, muW, Tw, nullptr);

  hipMemsetAsync(Spart, 0, (size_t)nslab * SLABTOT * sizeof(float), stream);
  em_sweep_legacy<1><<<dim3(BC), dim3(512), 0, stream>>>(x, W, muW, Tw, Spart, nslab);
  hipMemsetAsync(Sred, 0, SLABTOT * sizeof(float), stream);
  reduce_slabs<<<rgrid, dim3(256), 0, stream>>>(Spart, Sred, nslab, chunk);
  stats_post<1><<<dim3(1), dim3(512), 0, stream>>>(Sred, beta_v, beta_a, lam, nullptr, nullptr, out);
}